// Round 4
// baseline (2997.271 us; speedup 1.0000x reference)
//
#include <hip/hip_runtime.h>
#include <stdint.h>
#include <math.h>

// ---------- types / helpers ----------
typedef _Float16 f16x8 __attribute__((ext_vector_type(8)));
typedef float    f32x4 __attribute__((ext_vector_type(4)));

__device__ __forceinline__ unsigned short f2h(float x) {
    _Float16 h = (_Float16)x;                       // RN
    return __builtin_bit_cast(unsigned short, h);
}
__device__ __forceinline__ float h2f(unsigned short u) {
    return (float)__builtin_bit_cast(_Float16, u);
}

// Problem constants
// B=2, S=2048, Hid=2048, NH=16, NKV=4, D=128, chunks: 8 x 256, TOPK=4
//
// Two-path design:
//  GATE path (top-4 selection, needs exactness): fp64 GEMM for [q|k]
//    (4096x2560), rope with CR-fp32 angles/trig promoted to f64, fp64 kmean,
//    fp64 gate dots + top-4.  Error ~1e-13 -- no fp32-accumulator bias.
//  VALUE path (attention numerics, 2% tolerance): plain fp16 MFMA QKV GEMM,
//    fp32 rope (same trig tables), fp16 flash attention, fp16 out-proj.

// ================= phase 1: exact gate path =================

// ---------- CR-fp32 sincos tables: ct/st[s][i], s<2048, i<64 ----------
__global__ void sctab_kernel(float* __restrict__ ct, float* __restrict__ st) {
    int gid = blockIdx.x * 256 + threadIdx.x;   // 2048*64
    int i = gid & 63, s = gid >> 6;
    // np fp32: t = powf(1e4, i/64) [CR]; inv = 1.0f/t; ang = (f32)s * inv;
    // cos/sin = CR fp32 (glibc). (float)cos((double)ang) == CR cosf(ang).
    float xf = (float)i * (1.0f / 64.0f);           // exact
    float pf = (float)pow(10000.0, (double)xf);     // CR fp32 pow
    float inv = 1.0f / pf;                          // second fp32 rounding
    float ang = (float)s * inv;                     // fp32 product
    ct[gid] = (float)cos((double)ang);
    st[gid] = (float)sin((double)ang);
}

// ---------- fp64 GEMM: C64[4096][2560] = hs * [wq | wk] ----------
__global__ __launch_bounds__(256)
void gemm64_kernel(const float* __restrict__ hs, const float* __restrict__ wq,
                   const float* __restrict__ wk, double* __restrict__ C) {
    __shared__ double As[16][66];   // [kk][m], row stride 528 B (16B aligned)
    __shared__ double Bs[16][66];   // [kk][n]
    int n0 = blockIdx.x * 64, m0 = blockIdx.y * 64;
    const float* wsrc; int ldn, ncol0;
    if (n0 < 2048) { wsrc = wq; ldn = 2048; ncol0 = n0; }
    else           { wsrc = wk; ldn = 512;  ncol0 = n0 - 2048; }
    int t = threadIdx.x;
    int tx = t & 15, ty = t >> 4;
    int lm = t & 63, lk4 = (t >> 6) * 4;
    double acc[4][4] = {};
    for (int k0 = 0; k0 < 2048; k0 += 16) {
        __syncthreads();
        float4 a4 = *(const float4*)&hs[(size_t)(m0 + lm) * 2048 + k0 + lk4];
        As[lk4 + 0][lm] = (double)a4.x; As[lk4 + 1][lm] = (double)a4.y;
        As[lk4 + 2][lm] = (double)a4.z; As[lk4 + 3][lm] = (double)a4.w;
        #pragma unroll
        for (int u = 0; u < 4; ++u)
            Bs[lk4 + u][lm] = (double)wsrc[(size_t)(k0 + lk4 + u) * ldn + ncol0 + lm];
        __syncthreads();
        #pragma unroll
        for (int kk = 0; kk < 16; ++kk) {
            double a[4], b[4];
            #pragma unroll
            for (int i = 0; i < 4; ++i) a[i] = As[kk][ty * 4 + i];
            #pragma unroll
            for (int j = 0; j < 4; ++j) b[j] = Bs[kk][tx * 4 + j];
            #pragma unroll
            for (int i = 0; i < 4; ++i)
                #pragma unroll
                for (int j = 0; j < 4; ++j)
                    acc[i][j] = fma(a[i], b[j], acc[i][j]);
        }
    }
    #pragma unroll
    for (int i = 0; i < 4; ++i)
        #pragma unroll
        for (int j = 0; j < 4; ++j)
            C[(size_t)(m0 + ty * 4 + i) * 2560 + n0 + tx * 4 + j] = acc[i][j];
}

// ---------- fp64 RoPE in-place on q (heads 0..15) and k (16..19) ----------
__global__ void rope64_kernel(double* __restrict__ C, const float* __restrict__ ct,
                              const float* __restrict__ st) {
    int gid = blockIdx.x * 256 + threadIdx.x;   // 4096*20*64
    int i   = gid & 63;
    int rem = gid >> 6;
    int head = rem % 20;
    int m    = rem / 20;
    int s = m & 2047;
    double c  = (double)ct[s * 64 + i];
    double sn = (double)st[s * 64 + i];
    size_t base = (size_t)m * 2560 + head * 128;   // head*128 spans q then k
    double x1 = C[base + i], x2 = C[base + i + 64];
    C[base + i]      = x1 * c - x2 * sn;
    C[base + i + 64] = x2 * c + x1 * sn;
}

// ---------- fp64 chunk means of roped k ----------
__global__ void kmean64_kernel(const double* __restrict__ C, double* __restrict__ km) {
    int blk = blockIdx.x;               // b*32 + n*4 + kvh
    int b = blk >> 5, n = (blk >> 2) & 7, kvh = blk & 3;
    int d = threadIdx.x;                // 0..127
    double sum = 0.0;
    for (int r = 0; r < 256; ++r)
        sum += C[(size_t)(b * 2048 + n * 256 + r) * 2560 + 2048 + kvh * 128 + d];
    km[((b * 8 + n) * 4 + kvh) * 128 + d] = sum * (1.0 / 256.0);
}

// ---------- fp64 gate + top-4 -> bitmask per (b,h,s) ----------
__global__ void gate64_kernel(const double* __restrict__ C, const double* __restrict__ km,
                              unsigned int* __restrict__ maskbuf) {
    int wid  = (blockIdx.x * 256 + threadIdx.x) >> 6;  // (b,h,s) flat
    int lane = threadIdx.x & 63;
    int s = wid & 2047;
    int h = (wid >> 11) & 15;
    int b = wid >> 15;
    int kvh = h >> 2;
    size_t qb = (size_t)(b * 2048 + s) * 2560 + h * 128;
    double q0 = C[qb + lane], q1 = C[qb + 64 + lane];
    double g[8];
    #pragma unroll
    for (int n = 0; n < 8; ++n) {
        size_t kb = (size_t)((b * 8 + n) * 4 + kvh) * 128;
        double v = q0 * km[kb + lane] + q1 * km[kb + 64 + lane];
        #pragma unroll
        for (int off = 32; off; off >>= 1) v += __shfl_xor(v, off);
        g[n] = v;
    }
    int qc = s >> 8;
    const double INF = __builtin_inf();
    #pragma unroll
    for (int n = 0; n < 8; ++n) {
        if (n == qc)                g[n] = INF;
        else if (s < (n + 1) * 256) g[n] = -INF;
    }
    unsigned int msk = 0;
    for (int p = 0; p < 4; ++p) {   // iterative argmax, strict > => lowest index on ties
        double best = -INF; int bi = -1;
        #pragma unroll
        for (int n = 0; n < 8; ++n)
            if (!((msk >> n) & 1) && g[n] > best) { best = g[n]; bi = n; }
        if (bi >= 0) msk |= 1u << bi;
    }
    if (lane == 0) maskbuf[wid] = msk;
}

// ================= phase 2: fp16 value path =================

// ---------- hidden_states -> fp16 ----------
__global__ void split_kernel(const float* __restrict__ src,
                             unsigned short* __restrict__ hi, int n4) {
    int i = blockIdx.x * 256 + threadIdx.x;
    if (i >= n4) return;
    float4 v = ((const float4*)src)[i];
    ushort4 h;
    h.x = f2h(v.x); h.y = f2h(v.y); h.z = f2h(v.z); h.w = f2h(v.w);
    ((ushort4*)hi)[i] = h;
}

// ---------- pack [wq|wk|wv] transposed to Wt[n][k], fp16 ----------
__global__ void packw_kernel(const float* __restrict__ wq, const float* __restrict__ wk,
                             const float* __restrict__ wv, unsigned short* __restrict__ Wh) {
    int gid = blockIdx.x * 256 + threadIdx.x;   // 3072 * 512
    int n  = gid % 3072;
    int kg = gid / 3072;
    const float* src; int ldn, col;
    if (n < 2048)      { src = wq; ldn = 2048; col = n; }
    else if (n < 2560) { src = wk; ldn = 512;  col = n - 2048; }
    else               { src = wv; ldn = 512;  col = n - 2560; }
    int k0 = kg * 4;
    ushort4 h;
    h.x = f2h(src[(size_t)(k0 + 0) * ldn + col]);
    h.y = f2h(src[(size_t)(k0 + 1) * ldn + col]);
    h.z = f2h(src[(size_t)(k0 + 2) * ldn + col]);
    h.w = f2h(src[(size_t)(k0 + 3) * ldn + col]);
    *(ushort4*)&Wh[(size_t)n * 2048 + k0] = h;
}

// ---------- pack wo transposed ----------
__global__ void packwo_kernel(const float* __restrict__ wo, unsigned short* __restrict__ Wh) {
    int gid = blockIdx.x * 256 + threadIdx.x;   // 2048 * 512
    int n  = gid % 2048;
    int kg = gid / 2048;
    int k0 = kg * 4;
    ushort4 h;
    h.x = f2h(wo[(size_t)(k0 + 0) * 2048 + n]);
    h.y = f2h(wo[(size_t)(k0 + 1) * 2048 + n]);
    h.z = f2h(wo[(size_t)(k0 + 2) * 2048 + n]);
    h.w = f2h(wo[(size_t)(k0 + 3) * 2048 + n]);
    *(ushort4*)&Wh[(size_t)n * 2048 + k0] = h;
}

// ---------- fp16 MFMA GEMM: C(MxN fp32) = A(MxK) * B(KxN) ----------
__global__ __launch_bounds__(256, 2)
void gemm_kernel(const unsigned short* __restrict__ A_g, const unsigned short* __restrict__ B_g,
                 float* __restrict__ Cg, int M, int N, int K) {
    const int BK = 32;
    __shared__ unsigned short Ah[128][BK + 8];
    __shared__ unsigned short Bh[128][BK + 8];
    int n0 = blockIdx.x * 128, m0 = blockIdx.y * 128;
    int t = threadIdx.x;
    int wave = t >> 6, lane = t & 63;
    int quad = lane >> 4, l15 = lane & 15;
    int wm = (wave >> 1) * 64, wn = (wave & 1) * 64;

    f32x4 acc[4][4];
    f32x4 zero = {0.f, 0.f, 0.f, 0.f};
    for (int i = 0; i < 4; ++i)
        for (int j = 0; j < 4; ++j) acc[i][j] = zero;

    int srow = t >> 3;            // 0..31
    int scol = (t & 7) * 4;       // 0..28

    for (int k0 = 0; k0 < K; k0 += BK) {
        __syncthreads();
        #pragma unroll
        for (int it = 0; it < 4; ++it) {
            int r = srow + it * 32;
            *(ushort4*)&Ah[r][scol] = *(const ushort4*)&A_g[(size_t)(m0 + r) * K + k0 + scol];
            *(ushort4*)&Bh[r][scol] = *(const ushort4*)&B_g[(size_t)(n0 + r) * K + k0 + scol];
        }
        __syncthreads();
        f16x8 ah[4], bh[4];
        #pragma unroll
        for (int i = 0; i < 4; ++i) {
            ah[i] = *(const f16x8*)&Ah[wm + i * 16 + l15][quad * 8];
            bh[i] = *(const f16x8*)&Bh[wn + i * 16 + l15][quad * 8];
        }
        #pragma unroll
        for (int i = 0; i < 4; ++i)
            #pragma unroll
            for (int j = 0; j < 4; ++j)
                acc[i][j] = __builtin_amdgcn_mfma_f32_16x16x32_f16(ah[i], bh[j], acc[i][j], 0, 0, 0);
    }
    // C/D layout: col = lane&15, row = quad*4 + reg  [verified m89]
    #pragma unroll
    for (int i = 0; i < 4; ++i)
        #pragma unroll
        for (int j = 0; j < 4; ++j)
            #pragma unroll
            for (int r = 0; r < 4; ++r) {
                int row = m0 + wm + i * 16 + quad * 4 + r;
                int col = n0 + wn + j * 16 + l15;
                Cg[(size_t)row * N + col] = acc[i][j][r];
            }
}

// ---------- fp32 RoPE (value path) using the shared tables ----------
__global__ void rope_kernel(float* __restrict__ C, const float* __restrict__ ct,
                            const float* __restrict__ st) {
    int gid = blockIdx.x * 256 + threadIdx.x;   // 4096*20*64
    int i   = gid & 63;
    int rem = gid >> 6;
    int head = rem % 20;
    int m    = rem / 20;
    int s = m & 2047;
    float cs = ct[s * 64 + i], sn = st[s * 64 + i];
    size_t base = (size_t)m * 3072 + head * 128;
    float x1 = C[base + i], x2 = C[base + i + 64];
    C[base + i]      = x1 * cs - x2 * sn;
    C[base + i + 64] = x2 * cs + x1 * sn;
}

// ---------- flash attention over selected chunks (fp16 internals) ----------
__global__ __launch_bounds__(256, 2)
void attn_kernel(const float* __restrict__ C, const unsigned int* __restrict__ maskbuf,
                 unsigned short* __restrict__ Og) {
    __shared__ unsigned short q_s[64][128];  // fp16 q tile
    __shared__ unsigned short k_t[128][64];  // fp16 k, transposed [d][key]
    __shared__ unsigned short v_s[64][128];  // fp16 v
    __shared__ unsigned short p_s[64][64];   // fp16 probs
    int bid = blockIdx.x;                    // (b*16+h)*32 + qt
    int qt = bid & 31, h = (bid >> 5) & 15, b = bid >> 9;
    int t = threadIdx.x, tx = t & 15, ty = t >> 4;
    int q0 = qt * 64, qc = q0 >> 8, kvh = h >> 2;

    #pragma unroll
    for (int it = 0; it < 8; ++it) {
        int idx = t + it * 256;
        int r = idx >> 5, c = (idx & 31) * 4;
        float4 v4 = *(const float4*)&C[(size_t)(b * 2048 + q0 + r) * 3072 + h * 128 + c];
        ushort4 u; u.x = f2h(v4.x); u.y = f2h(v4.y); u.z = f2h(v4.z); u.w = f2h(v4.w);
        *(ushort4*)&q_s[r][c] = u;
    }
    unsigned int am[4];
    float m_i[4], l_i[4], o_acc[4][8];
    #pragma unroll
    for (int i = 0; i < 4; ++i) {
        am[i] = maskbuf[((b * 16 + h) << 11) + q0 + ty * 4 + i];
        m_i[i] = -__builtin_inff(); l_i[i] = 0.f;
        #pragma unroll
        for (int j = 0; j < 8; ++j) o_acc[i][j] = 0.f;
    }
    const float scale = 0.08838834764831845f;  // 1/sqrt(128)

    for (int c = 0; c <= qc; ++c) {
        int submax = (c == qc) ? ((q0 & 255) >> 6) : 3;
        for (int sub = 0; sub <= submax; ++sub) {
            int kbase = c * 256 + sub * 64;
            __syncthreads();
            #pragma unroll
            for (int it = 0; it < 8; ++it) {
                int idx = t + it * 256;
                int r = idx >> 5, cc = (idx & 31) * 4;
                size_t rowb = (size_t)(b * 2048 + kbase + r) * 3072;
                float4 kv = *(const float4*)&C[rowb + 2048 + kvh * 128 + cc];
                k_t[cc + 0][r] = f2h(kv.x); k_t[cc + 1][r] = f2h(kv.y);
                k_t[cc + 2][r] = f2h(kv.z); k_t[cc + 3][r] = f2h(kv.w);
                float4 vv = *(const float4*)&C[rowb + 2560 + kvh * 128 + cc];
                ushort4 u; u.x = f2h(vv.x); u.y = f2h(vv.y); u.z = f2h(vv.z); u.w = f2h(vv.w);
                *(ushort4*)&v_s[r][cc] = u;
            }
            __syncthreads();
            float s4[4][4];
            #pragma unroll
            for (int i = 0; i < 4; ++i)
                #pragma unroll
                for (int j = 0; j < 4; ++j) s4[i][j] = 0.f;
            for (int d = 0; d < 128; ++d) {
                ushort4 k4 = *(const ushort4*)&k_t[d][tx * 4];
                float kf0 = h2f(k4.x), kf1 = h2f(k4.y), kf2 = h2f(k4.z), kf3 = h2f(k4.w);
                #pragma unroll
                for (int i = 0; i < 4; ++i) {
                    float qv = h2f(q_s[ty * 4 + i][d]);
                    s4[i][0] += qv * kf0; s4[i][1] += qv * kf1;
                    s4[i][2] += qv * kf2; s4[i][3] += qv * kf3;
                }
            }
            #pragma unroll
            for (int i = 0; i < 4; ++i) {
                int qpos = q0 + ty * 4 + i;
                bool allow = (am[i] >> c) & 1;
                float sv[4], rmax = -__builtin_inff();
                #pragma unroll
                for (int j = 0; j < 4; ++j) {
                    int kpos = kbase + tx * 4 + j;
                    float x = s4[i][j] * scale;
                    if (!allow || kpos > qpos) x = -__builtin_inff();
                    sv[j] = x;
                    rmax = fmaxf(rmax, x);
                }
                #pragma unroll
                for (int off = 8; off; off >>= 1) rmax = fmaxf(rmax, __shfl_xor(rmax, off));
                float mnew = fmaxf(m_i[i], rmax);
                float alpha = (m_i[i] == -__builtin_inff()) ? 0.f : __expf(m_i[i] - mnew);
                float ps[4], lsum = 0.f;
                #pragma unroll
                for (int j = 0; j < 4; ++j) {
                    float p = (sv[j] == -__builtin_inff()) ? 0.f : __expf(sv[j] - mnew);
                    ps[j] = p; lsum += p;
                }
                #pragma unroll
                for (int off = 8; off; off >>= 1) lsum += __shfl_xor(lsum, off);
                l_i[i] = l_i[i] * alpha + lsum;
                m_i[i] = mnew;
                #pragma unroll
                for (int j = 0; j < 8; ++j) o_acc[i][j] *= alpha;
                ushort4 pu; pu.x = f2h(ps[0]); pu.y = f2h(ps[1]); pu.z = f2h(ps[2]); pu.w = f2h(ps[3]);
                *(ushort4*)&p_s[ty * 4 + i][tx * 4] = pu;
            }
            __syncthreads();
            for (int kk = 0; kk < 64; ++kk) {
                ushort4 va = *(const ushort4*)&v_s[kk][tx * 8];
                ushort4 vb = *(const ushort4*)&v_s[kk][tx * 8 + 4];
                float vf0 = h2f(va.x), vf1 = h2f(va.y), vf2 = h2f(va.z), vf3 = h2f(va.w);
                float vf4 = h2f(vb.x), vf5 = h2f(vb.y), vf6 = h2f(vb.z), vf7 = h2f(vb.w);
                #pragma unroll
                for (int i = 0; i < 4; ++i) {
                    float p = h2f(p_s[ty * 4 + i][kk]);
                    o_acc[i][0] += p * vf0; o_acc[i][1] += p * vf1;
                    o_acc[i][2] += p * vf2; o_acc[i][3] += p * vf3;
                    o_acc[i][4] += p * vf4; o_acc[i][5] += p * vf5;
                    o_acc[i][6] += p * vf6; o_acc[i][7] += p * vf7;
                }
            }
        }
    }
    #pragma unroll
    for (int i = 0; i < 4; ++i) {
        float inv = (l_i[i] > 0.f) ? 1.f / l_i[i] : 0.f;
        size_t ob = (size_t)(b * 2048 + q0 + ty * 4 + i) * 2048 + h * 128 + tx * 8;
        ushort4 u1, u2;
        u1.x = f2h(o_acc[i][0] * inv); u1.y = f2h(o_acc[i][1] * inv);
        u1.z = f2h(o_acc[i][2] * inv); u1.w = f2h(o_acc[i][3] * inv);
        u2.x = f2h(o_acc[i][4] * inv); u2.y = f2h(o_acc[i][5] * inv);
        u2.z = f2h(o_acc[i][6] * inv); u2.w = f2h(o_acc[i][7] * inv);
        *(ushort4*)&Og[ob] = u1;
        *(ushort4*)&Og[ob + 4] = u2;
    }
}

// ---------- launch ----------
extern "C" void kernel_launch(void* const* d_in, const int* in_sizes, int n_in,
                              void* d_out, int out_size, void* d_ws, size_t ws_size,
                              hipStream_t stream) {
    const float* hs = (const float*)d_in[0];
    const float* wq = (const float*)d_in[1];
    const float* wk = (const float*)d_in[2];
    const float* wv = (const float*)d_in[3];
    const float* wo = (const float*)d_in[4];
    float* out = (float*)d_out;
    char* ws = (char*)d_ws;

    // phase-1 buffer (dead after gate64):
    double*         C64  = (double*)       (ws + 0);           // 83.89 MB
    // phase-2 buffers (overlap C64 temporally):
    unsigned short* hsh  = (unsigned short*)(ws + 0);          // 16.78 MB
    unsigned short* Wth  = (unsigned short*)(ws + 16777216);   // 12.58 MB
    unsigned short* woth = (unsigned short*)(ws + 29360128);   //  8.39 MB
    float*          Cqkv = (float*)        (ws + 37748736);    // 50.33 MB (ends 88,080,384)
    unsigned short* Og   = (unsigned short*)(ws + 88080384);   // 16.78 MB (ends 104,857,600)
    // persistent across both phases:
    double*         km64 = (double*)       (ws + 104857600);   // 64 KB
    unsigned int*   mskb = (unsigned int*) (ws + 104923136);   // 512 KB
    float*          ct   = (float*)        (ws + 105447424);   // 512 KB
    float*          st   = (float*)        (ws + 105971712);   // 512 KB (total ~106.5 MB)

    // phase 1: exact gates
    sctab_kernel <<<512, 256, 0, stream>>>(ct, st);
    gemm64_kernel<<<dim3(40, 64), 256, 0, stream>>>(hs, wq, wk, C64);
    rope64_kernel<<<20480, 256, 0, stream>>>(C64, ct, st);
    kmean64_kernel<<<64, 128, 0, stream>>>(C64, km64);
    gate64_kernel<<<16384, 256, 0, stream>>>(C64, km64, mskb);
    // phase 2: fp16 value path
    split_kernel <<<8192, 256, 0, stream>>>(hs, hsh, 2097152);
    packw_kernel <<<6144, 256, 0, stream>>>(wq, wk, wv, Wth);
    packwo_kernel<<<4096, 256, 0, stream>>>(wo, woth);
    gemm_kernel  <<<dim3(24, 32), 256, 0, stream>>>(hsh, Wth, Cqkv, 4096, 3072, 2048);
    rope_kernel  <<<20480, 256, 0, stream>>>(Cqkv, ct, st);
    attn_kernel  <<<1024, 256, 0, stream>>>(Cqkv, mskb, Og);
    gemm_kernel  <<<dim3(16, 32), 256, 0, stream>>>(Og, woth, out, 4096, 2048, 2048);
}

// Round 5
// 1615.739 us; speedup vs baseline: 1.8550x; 1.8550x over previous
//
#include <hip/hip_runtime.h>
#include <stdint.h>
#include <math.h>

// ---------- types / helpers ----------
typedef _Float16 f16x8 __attribute__((ext_vector_type(8)));
typedef float    f32x4 __attribute__((ext_vector_type(4)));

__device__ __forceinline__ unsigned short f2h(float x) {
    _Float16 h = (_Float16)x;                       // RN
    return __builtin_bit_cast(unsigned short, h);
}
__device__ __forceinline__ float h2f(unsigned short u) {
    return (float)__builtin_bit_cast(_Float16, u);
}

// Problem constants
// B=2, S=2048, Hid=2048, NH=16, NKV=4, D=128, chunks: 8 x 256, TOPK=4
//
// Two-path design:
//  GATE path (top-4 selection, needs exactness): fp64 GEMM for [q|k],
//    CR-fp32 rope tables promoted to f64, fp64 kmean + gate + top-4.
//  VALUE path (2% tolerance): fp16 MFMA QKV GEMM, fp32 rope, fp16 MFMA
//    flash attention (this round's rewrite), fp16 MFMA out-proj.

// ================= phase 1: exact gate path =================

__global__ void sctab_kernel(float* __restrict__ ct, float* __restrict__ st) {
    int gid = blockIdx.x * 256 + threadIdx.x;   // 2048*64
    int i = gid & 63, s = gid >> 6;
    float xf = (float)i * (1.0f / 64.0f);           // exact
    float pf = (float)pow(10000.0, (double)xf);     // CR fp32 pow
    float inv = 1.0f / pf;                          // second fp32 rounding
    float ang = (float)s * inv;                     // fp32 product
    ct[gid] = (float)cos((double)ang);
    st[gid] = (float)sin((double)ang);
}

__global__ __launch_bounds__(256)
void gemm64_kernel(const float* __restrict__ hs, const float* __restrict__ wq,
                   const float* __restrict__ wk, double* __restrict__ C) {
    __shared__ double As[16][66];
    __shared__ double Bs[16][66];
    int n0 = blockIdx.x * 64, m0 = blockIdx.y * 64;
    const float* wsrc; int ldn, ncol0;
    if (n0 < 2048) { wsrc = wq; ldn = 2048; ncol0 = n0; }
    else           { wsrc = wk; ldn = 512;  ncol0 = n0 - 2048; }
    int t = threadIdx.x;
    int tx = t & 15, ty = t >> 4;
    int lm = t & 63, lk4 = (t >> 6) * 4;
    double acc[4][4] = {};
    for (int k0 = 0; k0 < 2048; k0 += 16) {
        __syncthreads();
        float4 a4 = *(const float4*)&hs[(size_t)(m0 + lm) * 2048 + k0 + lk4];
        As[lk4 + 0][lm] = (double)a4.x; As[lk4 + 1][lm] = (double)a4.y;
        As[lk4 + 2][lm] = (double)a4.z; As[lk4 + 3][lm] = (double)a4.w;
        #pragma unroll
        for (int u = 0; u < 4; ++u)
            Bs[lk4 + u][lm] = (double)wsrc[(size_t)(k0 + lk4 + u) * ldn + ncol0 + lm];
        __syncthreads();
        #pragma unroll
        for (int kk = 0; kk < 16; ++kk) {
            double a[4], b[4];
            #pragma unroll
            for (int i = 0; i < 4; ++i) a[i] = As[kk][ty * 4 + i];
            #pragma unroll
            for (int j = 0; j < 4; ++j) b[j] = Bs[kk][tx * 4 + j];
            #pragma unroll
            for (int i = 0; i < 4; ++i)
                #pragma unroll
                for (int j = 0; j < 4; ++j)
                    acc[i][j] = fma(a[i], b[j], acc[i][j]);
        }
    }
    #pragma unroll
    for (int i = 0; i < 4; ++i)
        #pragma unroll
        for (int j = 0; j < 4; ++j)
            C[(size_t)(m0 + ty * 4 + i) * 2560 + n0 + tx * 4 + j] = acc[i][j];
}

__global__ void rope64_kernel(double* __restrict__ C, const float* __restrict__ ct,
                              const float* __restrict__ st) {
    int gid = blockIdx.x * 256 + threadIdx.x;   // 4096*20*64
    int i   = gid & 63;
    int rem = gid >> 6;
    int head = rem % 20;
    int m    = rem / 20;
    int s = m & 2047;
    double c  = (double)ct[s * 64 + i];
    double sn = (double)st[s * 64 + i];
    size_t base = (size_t)m * 2560 + head * 128;
    double x1 = C[base + i], x2 = C[base + i + 64];
    C[base + i]      = x1 * c - x2 * sn;
    C[base + i + 64] = x2 * c + x1 * sn;
}

__global__ void kmean64_kernel(const double* __restrict__ C, double* __restrict__ km) {
    int blk = blockIdx.x;               // b*32 + n*4 + kvh
    int b = blk >> 5, n = (blk >> 2) & 7, kvh = blk & 3;
    int d = threadIdx.x;                // 0..127
    double sum = 0.0;
    for (int r = 0; r < 256; ++r)
        sum += C[(size_t)(b * 2048 + n * 256 + r) * 2560 + 2048 + kvh * 128 + d];
    km[((b * 8 + n) * 4 + kvh) * 128 + d] = sum * (1.0 / 256.0);
}

__global__ void gate64_kernel(const double* __restrict__ C, const double* __restrict__ km,
                              unsigned int* __restrict__ maskbuf) {
    int wid  = (blockIdx.x * 256 + threadIdx.x) >> 6;  // (b,h,s) flat
    int lane = threadIdx.x & 63;
    int s = wid & 2047;
    int h = (wid >> 11) & 15;
    int b = wid >> 15;
    int kvh = h >> 2;
    size_t qb = (size_t)(b * 2048 + s) * 2560 + h * 128;
    double q0 = C[qb + lane], q1 = C[qb + 64 + lane];
    double g[8];
    #pragma unroll
    for (int n = 0; n < 8; ++n) {
        size_t kb = (size_t)((b * 8 + n) * 4 + kvh) * 128;
        double v = q0 * km[kb + lane] + q1 * km[kb + 64 + lane];
        #pragma unroll
        for (int off = 32; off; off >>= 1) v += __shfl_xor(v, off);
        g[n] = v;
    }
    int qc = s >> 8;
    const double INF = __builtin_inf();
    #pragma unroll
    for (int n = 0; n < 8; ++n) {
        if (n == qc)                g[n] = INF;
        else if (s < (n + 1) * 256) g[n] = -INF;
    }
    unsigned int msk = 0;
    for (int p = 0; p < 4; ++p) {
        double best = -INF; int bi = -1;
        #pragma unroll
        for (int n = 0; n < 8; ++n)
            if (!((msk >> n) & 1) && g[n] > best) { best = g[n]; bi = n; }
        if (bi >= 0) msk |= 1u << bi;
    }
    if (lane == 0) maskbuf[wid] = msk;
}

// ================= phase 2: fp16 value path =================

__global__ void split_kernel(const float* __restrict__ src,
                             unsigned short* __restrict__ hi, int n4) {
    int i = blockIdx.x * 256 + threadIdx.x;
    if (i >= n4) return;
    float4 v = ((const float4*)src)[i];
    ushort4 h;
    h.x = f2h(v.x); h.y = f2h(v.y); h.z = f2h(v.z); h.w = f2h(v.w);
    ((ushort4*)hi)[i] = h;
}

__global__ void packw_kernel(const float* __restrict__ wq, const float* __restrict__ wk,
                             const float* __restrict__ wv, unsigned short* __restrict__ Wh) {
    int gid = blockIdx.x * 256 + threadIdx.x;   // 3072 * 512
    int n  = gid % 3072;
    int kg = gid / 3072;
    const float* src; int ldn, col;
    if (n < 2048)      { src = wq; ldn = 2048; col = n; }
    else if (n < 2560) { src = wk; ldn = 512;  col = n - 2048; }
    else               { src = wv; ldn = 512;  col = n - 2560; }
    int k0 = kg * 4;
    ushort4 h;
    h.x = f2h(src[(size_t)(k0 + 0) * ldn + col]);
    h.y = f2h(src[(size_t)(k0 + 1) * ldn + col]);
    h.z = f2h(src[(size_t)(k0 + 2) * ldn + col]);
    h.w = f2h(src[(size_t)(k0 + 3) * ldn + col]);
    *(ushort4*)&Wh[(size_t)n * 2048 + k0] = h;
}

__global__ void packwo_kernel(const float* __restrict__ wo, unsigned short* __restrict__ Wh) {
    int gid = blockIdx.x * 256 + threadIdx.x;   // 2048 * 512
    int n  = gid % 2048;
    int kg = gid / 2048;
    int k0 = kg * 4;
    ushort4 h;
    h.x = f2h(wo[(size_t)(k0 + 0) * 2048 + n]);
    h.y = f2h(wo[(size_t)(k0 + 1) * 2048 + n]);
    h.z = f2h(wo[(size_t)(k0 + 2) * 2048 + n]);
    h.w = f2h(wo[(size_t)(k0 + 3) * 2048 + n]);
    *(ushort4*)&Wh[(size_t)n * 2048 + k0] = h;
}

__global__ __launch_bounds__(256, 2)
void gemm_kernel(const unsigned short* __restrict__ A_g, const unsigned short* __restrict__ B_g,
                 float* __restrict__ Cg, int M, int N, int K) {
    const int BK = 32;
    __shared__ unsigned short Ah[128][BK + 8];
    __shared__ unsigned short Bh[128][BK + 8];
    int n0 = blockIdx.x * 128, m0 = blockIdx.y * 128;
    int t = threadIdx.x;
    int wave = t >> 6, lane = t & 63;
    int quad = lane >> 4, l15 = lane & 15;
    int wm = (wave >> 1) * 64, wn = (wave & 1) * 64;

    f32x4 acc[4][4];
    f32x4 zero = {0.f, 0.f, 0.f, 0.f};
    for (int i = 0; i < 4; ++i)
        for (int j = 0; j < 4; ++j) acc[i][j] = zero;

    int srow = t >> 3;
    int scol = (t & 7) * 4;

    for (int k0 = 0; k0 < K; k0 += BK) {
        __syncthreads();
        #pragma unroll
        for (int it = 0; it < 4; ++it) {
            int r = srow + it * 32;
            *(ushort4*)&Ah[r][scol] = *(const ushort4*)&A_g[(size_t)(m0 + r) * K + k0 + scol];
            *(ushort4*)&Bh[r][scol] = *(const ushort4*)&B_g[(size_t)(n0 + r) * K + k0 + scol];
        }
        __syncthreads();
        f16x8 ah[4], bh[4];
        #pragma unroll
        for (int i = 0; i < 4; ++i) {
            ah[i] = *(const f16x8*)&Ah[wm + i * 16 + l15][quad * 8];
            bh[i] = *(const f16x8*)&Bh[wn + i * 16 + l15][quad * 8];
        }
        #pragma unroll
        for (int i = 0; i < 4; ++i)
            #pragma unroll
            for (int j = 0; j < 4; ++j)
                acc[i][j] = __builtin_amdgcn_mfma_f32_16x16x32_f16(ah[i], bh[j], acc[i][j], 0, 0, 0);
    }
    #pragma unroll
    for (int i = 0; i < 4; ++i)
        #pragma unroll
        for (int j = 0; j < 4; ++j)
            #pragma unroll
            for (int r = 0; r < 4; ++r) {
                int row = m0 + wm + i * 16 + quad * 4 + r;
                int col = n0 + wn + j * 16 + l15;
                Cg[(size_t)row * N + col] = acc[i][j][r];
            }
}

__global__ void rope_kernel(float* __restrict__ C, const float* __restrict__ ct,
                            const float* __restrict__ st) {
    int gid = blockIdx.x * 256 + threadIdx.x;   // 4096*20*64
    int i   = gid & 63;
    int rem = gid >> 6;
    int head = rem % 20;
    int m    = rem / 20;
    int s = m & 2047;
    float cs = ct[s * 64 + i], sn = st[s * 64 + i];
    size_t base = (size_t)m * 3072 + head * 128;
    float x1 = C[base + i], x2 = C[base + i + 64];
    C[base + i]      = x1 * cs - x2 * sn;
    C[base + i + 64] = x2 * cs + x1 * sn;
}

// ---------- kv prep: K -> fp16 row-major, V -> fp16 transposed ----------
// Kh[b][kvh][key][dim], Vt[b][kvh][dim][key]
__global__ void kvprep_kernel(const float* __restrict__ C, unsigned short* __restrict__ Kh,
                              unsigned short* __restrict__ Vt) {
    __shared__ unsigned short vt[128][72];
    int blk = blockIdx.x;          // (b*4+kvh)*32 + kt
    int kt = blk & 31, kvh = (blk >> 5) & 3, b = blk >> 7;
    int t = threadIdx.x;
    int key0 = kt * 64;
    #pragma unroll
    for (int it = 0; it < 8; ++it) {
        int idx = t + it * 256;
        int r = idx >> 5, c = (idx & 31) * 4;       // key row r, dims c..c+3
        size_t rowb = (size_t)(b * 2048 + key0 + r) * 3072;
        float4 kv = *(const float4*)&C[rowb + 2048 + kvh * 128 + c];
        ushort4 u; u.x = f2h(kv.x); u.y = f2h(kv.y); u.z = f2h(kv.z); u.w = f2h(kv.w);
        *(ushort4*)&Kh[((size_t)(b * 4 + kvh) * 2048 + key0 + r) * 128 + c] = u;
        float4 vv = *(const float4*)&C[rowb + 2560 + kvh * 128 + c];
        vt[c + 0][r] = f2h(vv.x); vt[c + 1][r] = f2h(vv.y);
        vt[c + 2][r] = f2h(vv.z); vt[c + 3][r] = f2h(vv.w);
    }
    __syncthreads();
    #pragma unroll
    for (int it = 0; it < 8; ++it) {
        int idx = t + it * 256;
        int d = idx >> 4, c4 = (idx & 15) * 4;      // dim row d, keys c4..c4+3
        *(ushort4*)&Vt[((size_t)(b * 4 + kvh) * 128 + d) * 2048 + key0 + c4] =
            *(ushort4*)&vt[d][c4];
    }
}

// ---------- MFMA flash attention over selected chunks ----------
// Per block: (b, h, 64-query tile). 4 waves, each owns a 16-query strip.
// QK^T: A-frag = Q rows, B-frag = K rows (both [row][k] contiguous).
// softmax rows live in C-layout (row = quad*4+reg); row-reduce = shfl_xor<16.
// P round-trips LDS wave-privately (rows w16..w16+15) -> A-frag for PV.
// PV: B-frag = Vt rows ([dim][key]).
__global__ __launch_bounds__(256, 2)
void attn_kernel(const float* __restrict__ C, const unsigned short* __restrict__ Kh,
                 const unsigned short* __restrict__ Vt,
                 const unsigned int* __restrict__ maskbuf,
                 unsigned short* __restrict__ Og) {
    __shared__ unsigned short q_s[64][136];   // +8 pad: 2-way LDS aliasing (free)
    __shared__ unsigned short k_s[64][136];
    __shared__ unsigned short v_t[128][72];
    __shared__ unsigned short p_s[64][72];
    __shared__ unsigned int umask;
    int bid = blockIdx.x;                     // (b*16+h)*32 + qt
    int qt = bid & 31, h = (bid >> 5) & 15, b = bid >> 9;
    int t = threadIdx.x;
    int wave = t >> 6, lane = t & 63;
    int quad = lane >> 4, l15 = lane & 15;
    int w16 = wave * 16;
    int q0 = qt * 64, qc = q0 >> 8, kvh = h >> 2;
    const float NEGINF = -__builtin_inff();

    // stage Q (fp32 -> fp16)
    #pragma unroll
    for (int it = 0; it < 8; ++it) {
        int idx = t + it * 256;
        int r = idx >> 5, c = (idx & 31) * 4;
        float4 v4 = *(const float4*)&C[(size_t)(b * 2048 + q0 + r) * 3072 + h * 128 + c];
        ushort4 u; u.x = f2h(v4.x); u.y = f2h(v4.y); u.z = f2h(v4.z); u.w = f2h(v4.w);
        *(ushort4*)&q_s[r][c] = u;
    }
    if (t == 0) umask = 0;
    int mbase = ((b * 16 + h) << 11) + q0;
    unsigned int am[4];
    #pragma unroll
    for (int r = 0; r < 4; ++r)
        am[r] = maskbuf[mbase + w16 + quad * 4 + r];
    __syncthreads();
    if (t < 64) atomicOr(&umask, maskbuf[mbase + t]);
    // preload Q A-frags (q_s ready after barrier above)
    f16x8 aq[4];
    #pragma unroll
    for (int ks = 0; ks < 4; ++ks)
        aq[ks] = *(const f16x8*)&q_s[w16 + l15][ks * 32 + quad * 8];
    __syncthreads();
    unsigned int um = umask;

    float m_i[4], l_i[4];
    f32x4 o_acc[8];
    #pragma unroll
    for (int r = 0; r < 4; ++r) { m_i[r] = NEGINF; l_i[r] = 0.f; }
    #pragma unroll
    for (int n = 0; n < 8; ++n) o_acc[n] = (f32x4){0.f, 0.f, 0.f, 0.f};
    const float scale = 0.08838834764831845f;  // 1/sqrt(128)
    size_t khbase = (size_t)(b * 4 + kvh) * 2048 * 128;
    size_t vtbase = (size_t)(b * 4 + kvh) * 128 * 2048;

    for (int c = 0; c <= qc; ++c) {
        if (!((um >> c) & 1)) continue;
        int submax = (c == qc) ? ((q0 & 255) >> 6) : 3;
        for (int sub = 0; sub <= submax; ++sub) {
            int kbase = c * 256 + sub * 64;
            __syncthreads();
            #pragma unroll
            for (int it = 0; it < 8; ++it) {
                int idx = t + it * 256;
                int r = idx >> 5, cc = (idx & 31) * 4;
                *(ushort4*)&k_s[r][cc] =
                    *(const ushort4*)&Kh[khbase + (size_t)(kbase + r) * 128 + cc];
                int vr = idx >> 4, vc = (idx & 15) * 4;
                *(ushort4*)&v_t[vr][vc] =
                    *(const ushort4*)&Vt[vtbase + (size_t)vr * 2048 + kbase + vc];
            }
            __syncthreads();
            // S = Q K^T  (16q x 64k per wave)
            f32x4 s[4];
            #pragma unroll
            for (int j = 0; j < 4; ++j) {
                f32x4 sj = {0.f, 0.f, 0.f, 0.f};
                #pragma unroll
                for (int ks = 0; ks < 4; ++ks) {
                    f16x8 bf = *(const f16x8*)&k_s[j * 16 + l15][ks * 32 + quad * 8];
                    sj = __builtin_amdgcn_mfma_f32_16x16x32_f16(aq[ks], bf, sj, 0, 0, 0);
                }
                s[j] = sj;
            }
            // online softmax per row (row = quad*4 + r)
            #pragma unroll
            for (int r = 0; r < 4; ++r) {
                int qpos = q0 + w16 + quad * 4 + r;
                bool allow = (am[r] >> c) & 1;
                float sv[4], rmax = NEGINF;
                #pragma unroll
                for (int j = 0; j < 4; ++j) {
                    int kpos = kbase + j * 16 + l15;
                    float x = s[j][r] * scale;
                    if (!allow || kpos > qpos) x = NEGINF;
                    sv[j] = x;
                    rmax = fmaxf(rmax, x);
                }
                rmax = fmaxf(rmax, __shfl_xor(rmax, 1));
                rmax = fmaxf(rmax, __shfl_xor(rmax, 2));
                rmax = fmaxf(rmax, __shfl_xor(rmax, 4));
                rmax = fmaxf(rmax, __shfl_xor(rmax, 8));
                float mnew = fmaxf(m_i[r], rmax);
                float alpha = (m_i[r] == NEGINF) ? 0.f : __expf(m_i[r] - mnew);
                float ps[4], lsum = 0.f;
                #pragma unroll
                for (int j = 0; j < 4; ++j) {
                    float p = (sv[j] == NEGINF) ? 0.f : __expf(sv[j] - mnew);
                    ps[j] = p; lsum += p;
                }
                lsum += __shfl_xor(lsum, 1);
                lsum += __shfl_xor(lsum, 2);
                lsum += __shfl_xor(lsum, 4);
                lsum += __shfl_xor(lsum, 8);
                l_i[r] = l_i[r] * alpha + lsum;
                m_i[r] = mnew;
                #pragma unroll
                for (int n = 0; n < 8; ++n) o_acc[n][r] *= alpha;
                #pragma unroll
                for (int j = 0; j < 4; ++j)
                    p_s[w16 + quad * 4 + r][j * 16 + l15] = f2h(ps[j]);
            }
            // O += P V   (wave-private p_s round-trip; same-wave LDS is in-order)
            f16x8 pa0 = *(const f16x8*)&p_s[w16 + l15][quad * 8];
            f16x8 pa1 = *(const f16x8*)&p_s[w16 + l15][32 + quad * 8];
            #pragma unroll
            for (int n = 0; n < 8; ++n) {
                f16x8 b0 = *(const f16x8*)&v_t[n * 16 + l15][quad * 8];
                f16x8 b1 = *(const f16x8*)&v_t[n * 16 + l15][32 + quad * 8];
                o_acc[n] = __builtin_amdgcn_mfma_f32_16x16x32_f16(pa0, b0, o_acc[n], 0, 0, 0);
                o_acc[n] = __builtin_amdgcn_mfma_f32_16x16x32_f16(pa1, b1, o_acc[n], 0, 0, 0);
            }
        }
    }
    // epilogue: normalize, linearize via q_s, coalesced store
    __syncthreads();
    #pragma unroll
    for (int r = 0; r < 4; ++r) {
        float inv = (l_i[r] > 0.f) ? 1.f / l_i[r] : 0.f;
        #pragma unroll
        for (int n = 0; n < 8; ++n)
            q_s[w16 + quad * 4 + r][n * 16 + l15] = f2h(o_acc[n][r] * inv);
    }
    __syncthreads();
    #pragma unroll
    for (int it = 0; it < 8; ++it) {
        int idx = t + it * 256;
        int r = idx >> 5, cpos = (idx & 31) * 4;
        *(ushort4*)&Og[(size_t)(b * 2048 + q0 + r) * 2048 + h * 128 + cpos] =
            *(ushort4*)&q_s[r][cpos];
    }
}

// ---------- launch ----------
extern "C" void kernel_launch(void* const* d_in, const int* in_sizes, int n_in,
                              void* d_out, int out_size, void* d_ws, size_t ws_size,
                              hipStream_t stream) {
    const float* hs = (const float*)d_in[0];
    const float* wq = (const float*)d_in[1];
    const float* wk = (const float*)d_in[2];
    const float* wv = (const float*)d_in[3];
    const float* wo = (const float*)d_in[4];
    float* out = (float*)d_out;
    char* ws = (char*)d_ws;

    // phase-1 buffer (dead after gate64):
    double*         C64  = (double*)       (ws + 0);           // 83.89 MB
    // phase-2 buffers (overlap C64 temporally):
    unsigned short* hsh  = (unsigned short*)(ws + 0);          // 16.78 MB
    unsigned short* Wth  = (unsigned short*)(ws + 16777216);   // 12.58 MB
    unsigned short* woth = (unsigned short*)(ws + 29360128);   //  8.39 MB
    float*          Cqkv = (float*)        (ws + 37748736);    // 50.33 MB
    unsigned short* Og   = (unsigned short*)(ws + 88080384);   // 16.78 MB
    // persistent:
    double*         km64 = (double*)       (ws + 104857600);   // 64 KB
    unsigned int*   mskb = (unsigned int*) (ws + 104923136);   // 512 KB
    float*          ct   = (float*)        (ws + 105447424);   // 512 KB
    float*          st   = (float*)        (ws + 105971712);   // 512 KB
    unsigned short* Kh   = (unsigned short*)(ws + 106496000);  //  8.39 MB
    unsigned short* Vt   = (unsigned short*)(ws + 114884608);  //  8.39 MB (total ~123.3 MB)

    // phase 1: exact gates
    sctab_kernel <<<512, 256, 0, stream>>>(ct, st);
    gemm64_kernel<<<dim3(40, 64), 256, 0, stream>>>(hs, wq, wk, C64);
    rope64_kernel<<<20480, 256, 0, stream>>>(C64, ct, st);
    kmean64_kernel<<<64, 128, 0, stream>>>(C64, km64);
    gate64_kernel<<<16384, 256, 0, stream>>>(C64, km64, mskb);
    // phase 2: fp16 value path
    split_kernel <<<8192, 256, 0, stream>>>(hs, hsh, 2097152);
    packw_kernel <<<6144, 256, 0, stream>>>(wq, wk, wv, Wth);
    packwo_kernel<<<4096, 256, 0, stream>>>(wo, woth);
    gemm_kernel  <<<dim3(24, 32), 256, 0, stream>>>(hsh, Wth, Cqkv, 4096, 3072, 2048);
    rope_kernel  <<<20480, 256, 0, stream>>>(Cqkv, ct, st);
    kvprep_kernel<<<256, 256, 0, stream>>>(Cqkv, Kh, Vt);
    attn_kernel  <<<1024, 256, 0, stream>>>(Cqkv, Kh, Vt, mskb, Og);
    gemm_kernel  <<<dim3(16, 32), 256, 0, stream>>>(Og, woth, out, 4096, 2048, 2048);
}

// Round 6
// 905.509 us; speedup vs baseline: 3.3100x; 1.7843x over previous
//
#include <hip/hip_runtime.h>
#include <stdint.h>
#include <math.h>

// ---------- types / helpers ----------
typedef _Float16 f16x8 __attribute__((ext_vector_type(8)));
typedef float    f32x4 __attribute__((ext_vector_type(4)));

__device__ __forceinline__ unsigned short f2h(float x) {
    _Float16 h = (_Float16)x;
    return __builtin_bit_cast(unsigned short, h);
}
__device__ __forceinline__ float h2f(unsigned short u) {
    return (float)__builtin_bit_cast(_Float16, u);
}

// B=2, S=2048, Hid=2048, NH=16, NKV=4, D=128, chunks: 8 x 256, TOPK=4
//
// Gate strategy (margin-filtered repair):
//  - exact fp64 k GEMM (8.6 GFLOP) -> rope -> exact km64
//  - provisional gates from fp16-MFMA q (fp32 Cqkv) vs km64; gate noise
//    sigma ~1.3e-4.  margin < TAU=0.015 (~115 sigma) -> flag
//  - repair kernel: exact fp64 q matvec + gates for flagged queries only
// Value path: fp16 MFMA QKV GEMM, fp32 rope, fp16 MFMA flash attn, fp16 out-proj.

#define TAU 0.015

// ---------- CR-fp32 sincos tables ----------
__global__ void sctab_kernel(float* __restrict__ ct, float* __restrict__ st) {
    int gid = blockIdx.x * 256 + threadIdx.x;   // 2048*64
    int i = gid & 63, s = gid >> 6;
    float xf = (float)i * (1.0f / 64.0f);
    float pf = (float)pow(10000.0, (double)xf);     // CR fp32 pow
    float inv = 1.0f / pf;                          // second fp32 rounding (np)
    float ang = (float)s * inv;
    ct[gid] = (float)cos((double)ang);
    st[gid] = (float)sin((double)ang);
}

// ---------- fp64 k GEMM, 4-way K-split: Kp[kq][4096][512] ----------
__global__ __launch_bounds__(256)
void gemm64k_kernel(const float* __restrict__ hs, const float* __restrict__ wk,
                    double* __restrict__ Kp) {
    __shared__ double As[16][66];
    __shared__ double Bs[16][66];
    int n0 = blockIdx.x * 64, m0 = blockIdx.y * 64, kq = blockIdx.z;
    double* Cout = Kp + (size_t)kq * 4096 * 512;
    int t = threadIdx.x;
    int tx = t & 15, ty = t >> 4;
    int lm = t & 63, lk4 = (t >> 6) * 4;
    double acc[4][4] = {};
    int kbeg = kq * 512;
    for (int k0 = kbeg; k0 < kbeg + 512; k0 += 16) {
        __syncthreads();
        float4 a4 = *(const float4*)&hs[(size_t)(m0 + lm) * 2048 + k0 + lk4];
        As[lk4 + 0][lm] = (double)a4.x; As[lk4 + 1][lm] = (double)a4.y;
        As[lk4 + 2][lm] = (double)a4.z; As[lk4 + 3][lm] = (double)a4.w;
        #pragma unroll
        for (int u = 0; u < 4; ++u)
            Bs[lk4 + u][lm] = (double)wk[(size_t)(k0 + lk4 + u) * 512 + n0 + lm];
        __syncthreads();
        #pragma unroll
        for (int kk = 0; kk < 16; ++kk) {
            double a[4], b[4];
            #pragma unroll
            for (int i = 0; i < 4; ++i) a[i] = As[kk][ty * 4 + i];
            #pragma unroll
            for (int j = 0; j < 4; ++j) b[j] = Bs[kk][tx * 4 + j];
            #pragma unroll
            for (int i = 0; i < 4; ++i)
                #pragma unroll
                for (int j = 0; j < 4; ++j)
                    acc[i][j] = fma(a[i], b[j], acc[i][j]);
        }
    }
    #pragma unroll
    for (int i = 0; i < 4; ++i)
        #pragma unroll
        for (int j = 0; j < 4; ++j)
            Cout[(size_t)(m0 + ty * 4 + i) * 512 + n0 + tx * 4 + j] = acc[i][j];
}

// ---------- sum partials + fp64 rope -> K64[4096][512] ----------
__global__ void rope64k_kernel(const double* __restrict__ Kp, double* __restrict__ K64,
                               const float* __restrict__ ct, const float* __restrict__ st) {
    int gid = blockIdx.x * 256 + threadIdx.x;   // 4096 * 4 * 64
    int i   = gid & 63;
    int rem = gid >> 6;
    int kvh = rem & 3;
    int m   = rem >> 2;
    int s = m & 2047;
    size_t base = (size_t)m * 512 + kvh * 128;
    const size_t P = (size_t)4096 * 512;
    double x1 = Kp[base + i] + Kp[P + base + i] + Kp[2 * P + base + i] + Kp[3 * P + base + i];
    double x2 = Kp[base + i + 64] + Kp[P + base + i + 64] + Kp[2 * P + base + i + 64]
              + Kp[3 * P + base + i + 64];
    double c  = (double)ct[s * 64 + i];
    double sn = (double)st[s * 64 + i];
    K64[base + i]      = x1 * c - x2 * sn;
    K64[base + i + 64] = x2 * c + x1 * sn;
}

// ---------- exact fp64 chunk means ----------
__global__ void kmean64_kernel(const double* __restrict__ K64, double* __restrict__ km) {
    int blk = blockIdx.x;               // b*32 + n*4 + kvh
    int b = blk >> 5, n = (blk >> 2) & 7, kvh = blk & 3;
    int d = threadIdx.x;                // 0..127
    double sum = 0.0;
    for (int r = 0; r < 256; ++r)
        sum += K64[(size_t)(b * 2048 + n * 256 + r) * 512 + kvh * 128 + d];
    km[((b * 8 + n) * 4 + kvh) * 128 + d] = sum * (1.0 / 256.0);
}

// ---------- zero the flag counter ----------
__global__ void zeroflag_kernel(int* __restrict__ flagcnt) {
    if (threadIdx.x == 0 && blockIdx.x == 0) *flagcnt = 0;
}

// ---------- provisional gates (fp16-GEMM q vs exact km64) + margin flags ----------
__global__ void gatebase_kernel(const float* __restrict__ C, const double* __restrict__ km,
                                unsigned int* __restrict__ maskbuf,
                                int* __restrict__ flagcnt, int* __restrict__ flaglist) {
    int wid  = (blockIdx.x * 256 + threadIdx.x) >> 6;  // (b,h,s)
    int lane = threadIdx.x & 63;
    int s = wid & 2047;
    int h = (wid >> 11) & 15;
    int b = wid >> 15;
    int kvh = h >> 2;
    size_t qb = (size_t)(b * 2048 + s) * 3072 + h * 128;
    double q0 = (double)C[qb + lane], q1 = (double)C[qb + 64 + lane];
    double g[8];
    #pragma unroll
    for (int n = 0; n < 8; ++n) {
        size_t kb = (size_t)((b * 8 + n) * 4 + kvh) * 128;
        double v = q0 * km[kb + lane] + q1 * km[kb + 64 + lane];
        #pragma unroll
        for (int off = 32; off; off >>= 1) v += __shfl_xor(v, off);
        g[n] = v;
    }
    int qc = s >> 8;
    const double INF = __builtin_inf();
    #pragma unroll
    for (int n = 0; n < 8; ++n) {
        if (n == qc)                g[n] = INF;
        else if (s < (n + 1) * 256) g[n] = -INF;
    }
    unsigned int msk = 0;
    for (int p = 0; p < 4; ++p) {   // iterative argmax; strict > => lowest index on ties
        double best = -INF; int bi = -1;
        #pragma unroll
        for (int n = 0; n < 8; ++n)
            if (!((msk >> n) & 1) && g[n] > best) { best = g[n]; bi = n; }
        if (bi >= 0) msk |= 1u << bi;
    }
    if (lane == 0) {
        maskbuf[wid] = msk;
        if (qc >= 4) {   // only then can selection be ambiguous
            double worst_in = INF, best_out = -INF;
            #pragma unroll
            for (int n = 0; n < 8; ++n) {
                if ((msk >> n) & 1) worst_in = fmin(worst_in, g[n]);
                else if (g[n] > -1e300) best_out = fmax(best_out, g[n]);
            }
            if (worst_in - best_out < TAU) {
                int ix = atomicAdd(flagcnt, 1);
                flaglist[ix] = wid;
            }
        }
    }
}

// ---------- exact fp64 repair of flagged queries ----------
__global__ __launch_bounds__(256)
void repair_kernel(const float* __restrict__ hs, const float* __restrict__ wq,
                   const float* __restrict__ ct, const float* __restrict__ st,
                   const double* __restrict__ km, const int* __restrict__ flagcnt,
                   const int* __restrict__ flaglist, unsigned int* __restrict__ maskbuf) {
    __shared__ double red[256];
    __shared__ double qs[128];
    int nflag = *flagcnt;
    int t = threadIdx.x;
    int d = t & 127, half = t >> 7;
    for (int idx = blockIdx.x; idx < nflag; idx += gridDim.x) {
        int wid = flaglist[idx];
        int s = wid & 2047;
        int h = (wid >> 11) & 15;
        int b = wid >> 15;
        int kvh = h >> 2;
        // exact q matvec: q[d] = sum_k hs[s,k] * wq[k, h*128+d]
        const float* hrow = hs + (size_t)(b * 2048 + s) * 2048 + half * 1024;
        const float* wcol = wq + (size_t)half * 1024 * 2048 + h * 128 + d;
        double acc = 0.0;
        #pragma unroll 4
        for (int k = 0; k < 1024; ++k)
            acc = fma((double)hrow[k], (double)wcol[(size_t)k * 2048], acc);
        red[t] = acc;
        __syncthreads();
        if (t < 128) qs[t] = red[t] + red[t + 128];
        __syncthreads();
        if (t < 64) {   // rope (lanes touch disjoint pairs)
            double c  = (double)ct[s * 64 + t];
            double sn = (double)st[s * 64 + t];
            double x1 = qs[t], x2 = qs[t + 64];
            qs[t]      = x1 * c - x2 * sn;
            qs[t + 64] = x2 * c + x1 * sn;
        }
        __syncthreads();
        if (t < 64) {   // wave 0: exact gates + top-4
            double g[8];
            #pragma unroll
            for (int n = 0; n < 8; ++n) {
                size_t kb = (size_t)((b * 8 + n) * 4 + kvh) * 128;
                double v = qs[t] * km[kb + t] + qs[t + 64] * km[kb + 64 + t];
                #pragma unroll
                for (int off = 32; off; off >>= 1) v += __shfl_xor(v, off);
                g[n] = v;
            }
            int qc = s >> 8;
            const double INF = __builtin_inf();
            #pragma unroll
            for (int n = 0; n < 8; ++n) {
                if (n == qc)                g[n] = INF;
                else if (s < (n + 1) * 256) g[n] = -INF;
            }
            unsigned int msk = 0;
            for (int p = 0; p < 4; ++p) {
                double best = -INF; int bi = -1;
                #pragma unroll
                for (int n = 0; n < 8; ++n)
                    if (!((msk >> n) & 1) && g[n] > best) { best = g[n]; bi = n; }
                if (bi >= 0) msk |= 1u << bi;
            }
            if (t == 0) maskbuf[wid] = msk;
        }
        __syncthreads();
    }
}

// ================= fp16 value path =================

__global__ void split_kernel(const float* __restrict__ src,
                             unsigned short* __restrict__ hi, int n4) {
    int i = blockIdx.x * 256 + threadIdx.x;
    if (i >= n4) return;
    float4 v = ((const float4*)src)[i];
    ushort4 h;
    h.x = f2h(v.x); h.y = f2h(v.y); h.z = f2h(v.z); h.w = f2h(v.w);
    ((ushort4*)hi)[i] = h;
}

__global__ void packw_kernel(const float* __restrict__ wq, const float* __restrict__ wk,
                             const float* __restrict__ wv, unsigned short* __restrict__ Wh) {
    int gid = blockIdx.x * 256 + threadIdx.x;   // 3072 * 512
    int n  = gid % 3072;
    int kg = gid / 3072;
    const float* src; int ldn, col;
    if (n < 2048)      { src = wq; ldn = 2048; col = n; }
    else if (n < 2560) { src = wk; ldn = 512;  col = n - 2048; }
    else               { src = wv; ldn = 512;  col = n - 2560; }
    int k0 = kg * 4;
    ushort4 h;
    h.x = f2h(src[(size_t)(k0 + 0) * ldn + col]);
    h.y = f2h(src[(size_t)(k0 + 1) * ldn + col]);
    h.z = f2h(src[(size_t)(k0 + 2) * ldn + col]);
    h.w = f2h(src[(size_t)(k0 + 3) * ldn + col]);
    *(ushort4*)&Wh[(size_t)n * 2048 + k0] = h;
}

__global__ void packwo_kernel(const float* __restrict__ wo, unsigned short* __restrict__ Wh) {
    int gid = blockIdx.x * 256 + threadIdx.x;   // 2048 * 512
    int n  = gid % 2048;
    int kg = gid / 2048;
    int k0 = kg * 4;
    ushort4 h;
    h.x = f2h(wo[(size_t)(k0 + 0) * 2048 + n]);
    h.y = f2h(wo[(size_t)(k0 + 1) * 2048 + n]);
    h.z = f2h(wo[(size_t)(k0 + 2) * 2048 + n]);
    h.w = f2h(wo[(size_t)(k0 + 3) * 2048 + n]);
    *(ushort4*)&Wh[(size_t)n * 2048 + k0] = h;
}

__global__ __launch_bounds__(256, 2)
void gemm_kernel(const unsigned short* __restrict__ A_g, const unsigned short* __restrict__ B_g,
                 float* __restrict__ Cg, int M, int N, int K) {
    const int BK = 32;
    __shared__ unsigned short Ah[128][BK + 8];
    __shared__ unsigned short Bh[128][BK + 8];
    int n0 = blockIdx.x * 128, m0 = blockIdx.y * 128;
    int t = threadIdx.x;
    int wave = t >> 6, lane = t & 63;
    int quad = lane >> 4, l15 = lane & 15;
    int wm = (wave >> 1) * 64, wn = (wave & 1) * 64;

    f32x4 acc[4][4];
    f32x4 zero = {0.f, 0.f, 0.f, 0.f};
    for (int i = 0; i < 4; ++i)
        for (int j = 0; j < 4; ++j) acc[i][j] = zero;

    int srow = t >> 3;
    int scol = (t & 7) * 4;

    for (int k0 = 0; k0 < K; k0 += BK) {
        __syncthreads();
        #pragma unroll
        for (int it = 0; it < 4; ++it) {
            int r = srow + it * 32;
            *(ushort4*)&Ah[r][scol] = *(const ushort4*)&A_g[(size_t)(m0 + r) * K + k0 + scol];
            *(ushort4*)&Bh[r][scol] = *(const ushort4*)&B_g[(size_t)(n0 + r) * K + k0 + scol];
        }
        __syncthreads();
        f16x8 ah[4], bh[4];
        #pragma unroll
        for (int i = 0; i < 4; ++i) {
            ah[i] = *(const f16x8*)&Ah[wm + i * 16 + l15][quad * 8];
            bh[i] = *(const f16x8*)&Bh[wn + i * 16 + l15][quad * 8];
        }
        #pragma unroll
        for (int i = 0; i < 4; ++i)
            #pragma unroll
            for (int j = 0; j < 4; ++j)
                acc[i][j] = __builtin_amdgcn_mfma_f32_16x16x32_f16(ah[i], bh[j], acc[i][j], 0, 0, 0);
    }
    #pragma unroll
    for (int i = 0; i < 4; ++i)
        #pragma unroll
        for (int j = 0; j < 4; ++j)
            #pragma unroll
            for (int r = 0; r < 4; ++r) {
                int row = m0 + wm + i * 16 + quad * 4 + r;
                int col = n0 + wn + j * 16 + l15;
                Cg[(size_t)row * N + col] = acc[i][j][r];
            }
}

__global__ void rope_kernel(float* __restrict__ C, const float* __restrict__ ct,
                            const float* __restrict__ st) {
    int gid = blockIdx.x * 256 + threadIdx.x;   // 4096*20*64
    int i   = gid & 63;
    int rem = gid >> 6;
    int head = rem % 20;
    int m    = rem / 20;
    int s = m & 2047;
    float cs = ct[s * 64 + i], sn = st[s * 64 + i];
    size_t base = (size_t)m * 3072 + head * 128;
    float x1 = C[base + i], x2 = C[base + i + 64];
    C[base + i]      = x1 * cs - x2 * sn;
    C[base + i + 64] = x2 * cs + x1 * sn;
}

// ---------- kv prep: K -> fp16 row-major, V -> fp16 transposed ----------
__global__ void kvprep_kernel(const float* __restrict__ C, unsigned short* __restrict__ Kh,
                              unsigned short* __restrict__ Vt) {
    __shared__ unsigned short vt[128][72];
    int blk = blockIdx.x;          // (b*4+kvh)*32 + kt
    int kt = blk & 31, kvh = (blk >> 5) & 3, b = blk >> 7;
    int t = threadIdx.x;
    int key0 = kt * 64;
    #pragma unroll
    for (int it = 0; it < 8; ++it) {
        int idx = t + it * 256;
        int r = idx >> 5, c = (idx & 31) * 4;
        size_t rowb = (size_t)(b * 2048 + key0 + r) * 3072;
        float4 kv = *(const float4*)&C[rowb + 2048 + kvh * 128 + c];
        ushort4 u; u.x = f2h(kv.x); u.y = f2h(kv.y); u.z = f2h(kv.z); u.w = f2h(kv.w);
        *(ushort4*)&Kh[((size_t)(b * 4 + kvh) * 2048 + key0 + r) * 128 + c] = u;
        float4 vv = *(const float4*)&C[rowb + 2560 + kvh * 128 + c];
        vt[c + 0][r] = f2h(vv.x); vt[c + 1][r] = f2h(vv.y);
        vt[c + 2][r] = f2h(vv.z); vt[c + 3][r] = f2h(vv.w);
    }
    __syncthreads();
    #pragma unroll
    for (int it = 0; it < 8; ++it) {
        int idx = t + it * 256;
        int d = idx >> 4, c4 = (idx & 15) * 4;
        *(ushort4*)&Vt[((size_t)(b * 4 + kvh) * 128 + d) * 2048 + key0 + c4] =
            *(ushort4*)&vt[d][c4];
    }
}

// ---------- MFMA flash attention ----------
__global__ __launch_bounds__(256, 2)
void attn_kernel(const float* __restrict__ C, const unsigned short* __restrict__ Kh,
                 const unsigned short* __restrict__ Vt,
                 const unsigned int* __restrict__ maskbuf,
                 unsigned short* __restrict__ Og) {
    __shared__ unsigned short q_s[64][136];
    __shared__ unsigned short k_s[64][136];
    __shared__ unsigned short v_t[128][72];
    __shared__ unsigned short p_s[64][72];
    __shared__ unsigned int umask;
    int bid = blockIdx.x;                     // (b*16+h)*32 + qt
    int qt = bid & 31, h = (bid >> 5) & 15, b = bid >> 9;
    int t = threadIdx.x;
    int wave = t >> 6, lane = t & 63;
    int quad = lane >> 4, l15 = lane & 15;
    int w16 = wave * 16;
    int q0 = qt * 64, qc = q0 >> 8, kvh = h >> 2;
    const float NEGINF = -__builtin_inff();

    #pragma unroll
    for (int it = 0; it < 8; ++it) {
        int idx = t + it * 256;
        int r = idx >> 5, c = (idx & 31) * 4;
        float4 v4 = *(const float4*)&C[(size_t)(b * 2048 + q0 + r) * 3072 + h * 128 + c];
        ushort4 u; u.x = f2h(v4.x); u.y = f2h(v4.y); u.z = f2h(v4.z); u.w = f2h(v4.w);
        *(ushort4*)&q_s[r][c] = u;
    }
    if (t == 0) umask = 0;
    int mbase = ((b * 16 + h) << 11) + q0;
    unsigned int am[4];
    #pragma unroll
    for (int r = 0; r < 4; ++r)
        am[r] = maskbuf[mbase + w16 + quad * 4 + r];
    __syncthreads();
    if (t < 64) atomicOr(&umask, maskbuf[mbase + t]);
    f16x8 aq[4];
    #pragma unroll
    for (int ks = 0; ks < 4; ++ks)
        aq[ks] = *(const f16x8*)&q_s[w16 + l15][ks * 32 + quad * 8];
    __syncthreads();
    unsigned int um = umask;

    float m_i[4], l_i[4];
    f32x4 o_acc[8];
    #pragma unroll
    for (int r = 0; r < 4; ++r) { m_i[r] = NEGINF; l_i[r] = 0.f; }
    #pragma unroll
    for (int n = 0; n < 8; ++n) o_acc[n] = (f32x4){0.f, 0.f, 0.f, 0.f};
    const float scale = 0.08838834764831845f;
    size_t khbase = (size_t)(b * 4 + kvh) * 2048 * 128;
    size_t vtbase = (size_t)(b * 4 + kvh) * 128 * 2048;

    for (int c = 0; c <= qc; ++c) {
        if (!((um >> c) & 1)) continue;
        int submax = (c == qc) ? ((q0 & 255) >> 6) : 3;
        for (int sub = 0; sub <= submax; ++sub) {
            int kbase = c * 256 + sub * 64;
            __syncthreads();
            #pragma unroll
            for (int it = 0; it < 8; ++it) {
                int idx = t + it * 256;
                int r = idx >> 5, cc = (idx & 31) * 4;
                *(ushort4*)&k_s[r][cc] =
                    *(const ushort4*)&Kh[khbase + (size_t)(kbase + r) * 128 + cc];
                int vr = idx >> 4, vc = (idx & 15) * 4;
                *(ushort4*)&v_t[vr][vc] =
                    *(const ushort4*)&Vt[vtbase + (size_t)vr * 2048 + kbase + vc];
            }
            __syncthreads();
            f32x4 s[4];
            #pragma unroll
            for (int j = 0; j < 4; ++j) {
                f32x4 sj = {0.f, 0.f, 0.f, 0.f};
                #pragma unroll
                for (int ks = 0; ks < 4; ++ks) {
                    f16x8 bf = *(const f16x8*)&k_s[j * 16 + l15][ks * 32 + quad * 8];
                    sj = __builtin_amdgcn_mfma_f32_16x16x32_f16(aq[ks], bf, sj, 0, 0, 0);
                }
                s[j] = sj;
            }
            #pragma unroll
            for (int r = 0; r < 4; ++r) {
                int qpos = q0 + w16 + quad * 4 + r;
                bool allow = (am[r] >> c) & 1;
                float sv[4], rmax = NEGINF;
                #pragma unroll
                for (int j = 0; j < 4; ++j) {
                    int kpos = kbase + j * 16 + l15;
                    float x = s[j][r] * scale;
                    if (!allow || kpos > qpos) x = NEGINF;
                    sv[j] = x;
                    rmax = fmaxf(rmax, x);
                }
                rmax = fmaxf(rmax, __shfl_xor(rmax, 1));
                rmax = fmaxf(rmax, __shfl_xor(rmax, 2));
                rmax = fmaxf(rmax, __shfl_xor(rmax, 4));
                rmax = fmaxf(rmax, __shfl_xor(rmax, 8));
                float mnew = fmaxf(m_i[r], rmax);
                float alpha = (m_i[r] == NEGINF) ? 0.f : __expf(m_i[r] - mnew);
                float ps[4], lsum = 0.f;
                #pragma unroll
                for (int j = 0; j < 4; ++j) {
                    float p = (sv[j] == NEGINF) ? 0.f : __expf(sv[j] - mnew);
                    ps[j] = p; lsum += p;
                }
                lsum += __shfl_xor(lsum, 1);
                lsum += __shfl_xor(lsum, 2);
                lsum += __shfl_xor(lsum, 4);
                lsum += __shfl_xor(lsum, 8);
                l_i[r] = l_i[r] * alpha + lsum;
                m_i[r] = mnew;
                #pragma unroll
                for (int n = 0; n < 8; ++n) o_acc[n][r] *= alpha;
                #pragma unroll
                for (int j = 0; j < 4; ++j)
                    p_s[w16 + quad * 4 + r][j * 16 + l15] = f2h(ps[j]);
            }
            f16x8 pa0 = *(const f16x8*)&p_s[w16 + l15][quad * 8];
            f16x8 pa1 = *(const f16x8*)&p_s[w16 + l15][32 + quad * 8];
            #pragma unroll
            for (int n = 0; n < 8; ++n) {
                f16x8 b0 = *(const f16x8*)&v_t[n * 16 + l15][quad * 8];
                f16x8 b1 = *(const f16x8*)&v_t[n * 16 + l15][32 + quad * 8];
                o_acc[n] = __builtin_amdgcn_mfma_f32_16x16x32_f16(pa0, b0, o_acc[n], 0, 0, 0);
                o_acc[n] = __builtin_amdgcn_mfma_f32_16x16x32_f16(pa1, b1, o_acc[n], 0, 0, 0);
            }
        }
    }
    __syncthreads();
    #pragma unroll
    for (int r = 0; r < 4; ++r) {
        float inv = (l_i[r] > 0.f) ? 1.f / l_i[r] : 0.f;
        #pragma unroll
        for (int n = 0; n < 8; ++n)
            q_s[w16 + quad * 4 + r][n * 16 + l15] = f2h(o_acc[n][r] * inv);
    }
    __syncthreads();
    #pragma unroll
    for (int it = 0; it < 8; ++it) {
        int idx = t + it * 256;
        int r = idx >> 5, cpos = (idx & 31) * 4;
        *(ushort4*)&Og[(size_t)(b * 2048 + q0 + r) * 2048 + h * 128 + cpos] =
            *(ushort4*)&q_s[r][cpos];
    }
}

// ---------- launch ----------
extern "C" void kernel_launch(void* const* d_in, const int* in_sizes, int n_in,
                              void* d_out, int out_size, void* d_ws, size_t ws_size,
                              hipStream_t stream) {
    const float* hs = (const float*)d_in[0];
    const float* wq = (const float*)d_in[1];
    const float* wk = (const float*)d_in[2];
    const float* wv = (const float*)d_in[3];
    const float* wo = (const float*)d_in[4];
    float* out = (float*)d_out;
    char* ws = (char*)d_ws;

    // phase-1 (gate) buffers, overlapped with phase-2 regions:
    double*         K64  = (double*)       (ws + 0);           // 16.78 MB (reused by hsh)
    double*         Kp   = (double*)       (ws + 37748736);    // 67.11 MB (reused by Cqkv/Og)
    // phase-2 buffers:
    unsigned short* hsh  = (unsigned short*)(ws + 0);          // 16.78 MB
    unsigned short* Wth  = (unsigned short*)(ws + 16777216);   // 12.58 MB
    unsigned short* woth = (unsigned short*)(ws + 29360128);   //  8.39 MB
    float*          Cqkv = (float*)        (ws + 37748736);    // 50.33 MB
    unsigned short* Og   = (unsigned short*)(ws + 88080384);   // 16.78 MB
    // persistent:
    double*         km64 = (double*)       (ws + 104857600);   // 64 KB
    unsigned int*   mskb = (unsigned int*) (ws + 104923136);   // 512 KB
    float*          ct   = (float*)        (ws + 105447424);   // 512 KB
    float*          st   = (float*)        (ws + 105971712);   // 512 KB
    unsigned short* Kh   = (unsigned short*)(ws + 106496000);  //  8.39 MB
    unsigned short* Vt   = (unsigned short*)(ws + 114884608);  //  8.39 MB
    int*            fcnt = (int*)          (ws + 123273216);   // 64 B
    int*            flst = (int*)          (ws + 123273280);   // 256 KB (total ~123.5 MB)

    // phase 1: exact km64
    sctab_kernel  <<<512, 256, 0, stream>>>(ct, st);
    gemm64k_kernel<<<dim3(8, 64, 4), 256, 0, stream>>>(hs, wk, Kp);
    rope64k_kernel<<<4096, 256, 0, stream>>>(Kp, K64, ct, st);
    kmean64_kernel<<<64, 128, 0, stream>>>(K64, km64);
    // phase 2: fp16 value path (also feeds provisional gates)
    split_kernel  <<<8192, 256, 0, stream>>>(hs, hsh, 2097152);
    packw_kernel  <<<6144, 256, 0, stream>>>(wq, wk, wv, Wth);
    packwo_kernel <<<4096, 256, 0, stream>>>(wo, woth);
    gemm_kernel   <<<dim3(24, 32), 256, 0, stream>>>(hsh, Wth, Cqkv, 4096, 3072, 2048);
    rope_kernel   <<<20480, 256, 0, stream>>>(Cqkv, ct, st);
    // gates: provisional + margin-filtered exact repair
    zeroflag_kernel<<<1, 64, 0, stream>>>(fcnt);
    gatebase_kernel<<<16384, 256, 0, stream>>>(Cqkv, km64, mskb, fcnt, flst);
    repair_kernel <<<2048, 256, 0, stream>>>(hs, wq, ct, st, km64, fcnt, flst, mskb);
    // attention + out-proj
    kvprep_kernel <<<256, 256, 0, stream>>>(Cqkv, Kh, Vt);
    attn_kernel   <<<1024, 256, 0, stream>>>(Cqkv, Kh, Vt, mskb, Og);
    gemm_kernel   <<<dim3(16, 32), 256, 0, stream>>>(Og, woth, out, 4096, 2048, 2048);
}

// Round 7
// 853.589 us; speedup vs baseline: 3.5114x; 1.0608x over previous
//
#include <hip/hip_runtime.h>
#include <stdint.h>
#include <math.h>

// ---------- types / helpers ----------
typedef _Float16 f16x8 __attribute__((ext_vector_type(8)));
typedef float    f32x4 __attribute__((ext_vector_type(4)));

__device__ __forceinline__ unsigned short f2h(float x) {
    _Float16 h = (_Float16)x;
    return __builtin_bit_cast(unsigned short, h);
}
__device__ __forceinline__ float h2f(unsigned short u) {
    return (float)__builtin_bit_cast(_Float16, u);
}

// B=2, S=2048, Hid=2048, NH=16, NKV=4, D=128, chunks: 8 x 256, TOPK=4
//
// Gate strategy (margin-filtered repair):
//  - exact fp64 kmean via rope-factorization: kmean needs only chunk sums of
//    roped k; rope is elementwise-linear, so
//      kmean[n,i] = sum_h Ac[n,i,h] wk[h,i] -/+ sum_h As[n,i,h] wk[h,i+-64]
//    with Ac/As[n,i,h] = sum_{s in chunk} cos/sin(s,i) hs[s,h].
//    2.3 GFLOP fp64 instead of the 8.6 GFLOP fp64 k-GEMM (R6's 247 us top dispatch).
//  - provisional gates from fp16-MFMA q (fp32 Cqkv) vs exact km64; margin <
//    TAU=0.015 (~115 sigma of gate noise) -> exact fp64 repair of that query.
// Value path: fp16 MFMA QKV GEMM, fp32 rope, fp16 MFMA flash attn, fp16 out-proj.

#define TAU 0.015

// ---------- CR-fp32 sincos tables ----------
__global__ void sctab_kernel(float* __restrict__ ct, float* __restrict__ st) {
    int gid = blockIdx.x * 256 + threadIdx.x;   // 2048*64
    int i = gid & 63, s = gid >> 6;
    float xf = (float)i * (1.0f / 64.0f);
    float pf = (float)pow(10000.0, (double)xf);     // CR fp32 pow
    float inv = 1.0f / pf;                          // second fp32 rounding (np)
    float ang = (float)s * inv;
    ct[gid] = (float)cos((double)ang);
    st[gid] = (float)sin((double)ang);
}

// ---------- trig-weighted chunk sums: Act/Ast[bn][h][d] (fp64) ----------
// Act[bn][h][d] = sum_{s in chunk} cos(s,d) * hs[b][n*256+s][h]   (Ast: sin)
__global__ __launch_bounds__(256)
void ksum_kernel(const float* __restrict__ hs, const float* __restrict__ ct,
                 const float* __restrict__ st, double* __restrict__ Act,
                 double* __restrict__ Ast) {
    __shared__ float Hs[16][68];
    __shared__ float Tc[16][68];
    __shared__ float Ts[16][68];
    int bn = blockIdx.y;             // b*8 + n
    int h0 = blockIdx.x * 64;
    int b = bn >> 3, n = bn & 7;
    int t = threadIdx.x;
    int tx = t & 15, ty = t >> 4;
    int d0 = tx * 4, hl0 = ty * 4;
    int si = t & 15, g4 = (t >> 4) * 4;
    double ac[4][4] = {}, as_[4][4] = {};
    for (int s0 = 0; s0 < 256; s0 += 16) {
        __syncthreads();
        int srow = n * 256 + s0 + si;
        *(float4*)&Hs[si][g4] = *(const float4*)&hs[(size_t)(b * 2048 + srow) * 2048 + h0 + g4];
        *(float4*)&Tc[si][g4] = *(const float4*)&ct[srow * 64 + g4];
        *(float4*)&Ts[si][g4] = *(const float4*)&st[srow * 64 + g4];
        __syncthreads();
        #pragma unroll
        for (int kk = 0; kk < 16; ++kk) {
            double hv[4], cv[4], sv[4];
            #pragma unroll
            for (int j = 0; j < 4; ++j) hv[j] = (double)Hs[kk][hl0 + j];
            #pragma unroll
            for (int i = 0; i < 4; ++i) { cv[i] = (double)Tc[kk][d0 + i]; sv[i] = (double)Ts[kk][d0 + i]; }
            #pragma unroll
            for (int i = 0; i < 4; ++i)
                #pragma unroll
                for (int j = 0; j < 4; ++j) {
                    ac[i][j]  = fma(cv[i], hv[j], ac[i][j]);
                    as_[i][j] = fma(sv[i], hv[j], as_[i][j]);
                }
        }
    }
    #pragma unroll
    for (int j = 0; j < 4; ++j) {
        size_t rb = ((size_t)bn * 2048 + h0 + hl0 + j) * 64 + d0;
        double2 c0 = {ac[0][j], ac[1][j]},  c1 = {ac[2][j], ac[3][j]};
        double2 s0_ = {as_[0][j], as_[1][j]}, s1_ = {as_[2][j], as_[3][j]};
        *(double2*)&Act[rb] = c0; *(double2*)&Act[rb + 2] = c1;
        *(double2*)&Ast[rb] = s0_; *(double2*)&Ast[rb + 2] = s1_;
    }
}

// ---------- zero km64 ----------
__global__ void kmzero_kernel(double* __restrict__ km) {
    int i = blockIdx.x * 256 + threadIdx.x;
    if (i < 8192) km[i] = 0.0;
}

// ---------- contract Act/Ast with wk -> exact km64 ----------
__global__ __launch_bounds__(256)
void kmeanw_kernel(const double* __restrict__ Act, const double* __restrict__ Ast,
                   const float* __restrict__ wk, double* __restrict__ km) {
    __shared__ double red[256];
    int blk = blockIdx.x;            // (bn*4 + kvh)*4 + hp
    int hp = blk & 3, kvh = (blk >> 2) & 3, bn = blk >> 4;
    int t = threadIdx.x;
    int d = t & 127, sub = t >> 7;
    int jj = d & 63;
    int col1 = kvh * 128 + d;
    int col2 = kvh * 128 + (d ^ 64);
    double sgn = (d < 64) ? -1.0 : 1.0;   // i<64: -sin term; i>=64: +sin term
    const double* actb = Act + (size_t)bn * 2048 * 64;
    const double* astb = Ast + (size_t)bn * 2048 * 64;
    double acc1 = 0.0, acc2 = 0.0;
    int hbeg = hp * 512 + sub * 256;
    for (int h = hbeg; h < hbeg + 256; ++h) {
        acc1 = fma(actb[(size_t)h * 64 + jj], (double)wk[(size_t)h * 512 + col1], acc1);
        acc2 = fma(astb[(size_t)h * 64 + jj], (double)wk[(size_t)h * 512 + col2], acc2);
    }
    red[t] = acc1 + sgn * acc2;
    __syncthreads();
    if (t < 128) {
        double v = red[t] + red[t + 128];
        atomicAdd(&km[((size_t)bn * 4 + kvh) * 128 + d], v * (1.0 / 256.0));
    }
}

// ---------- zero the flag counter ----------
__global__ void zeroflag_kernel(int* __restrict__ flagcnt) {
    if (threadIdx.x == 0 && blockIdx.x == 0) *flagcnt = 0;
}

// ---------- provisional gates (fp16-GEMM q vs exact km64) + margin flags ----------
__global__ void gatebase_kernel(const float* __restrict__ C, const double* __restrict__ km,
                                unsigned int* __restrict__ maskbuf,
                                int* __restrict__ flagcnt, int* __restrict__ flaglist) {
    int wid  = (blockIdx.x * 256 + threadIdx.x) >> 6;  // (b,h,s)
    int lane = threadIdx.x & 63;
    int s = wid & 2047;
    int h = (wid >> 11) & 15;
    int b = wid >> 15;
    int kvh = h >> 2;
    size_t qb = (size_t)(b * 2048 + s) * 3072 + h * 128;
    double q0 = (double)C[qb + lane], q1 = (double)C[qb + 64 + lane];
    double g[8];
    #pragma unroll
    for (int n = 0; n < 8; ++n) {
        size_t kb = (size_t)((b * 8 + n) * 4 + kvh) * 128;
        double v = q0 * km[kb + lane] + q1 * km[kb + 64 + lane];
        #pragma unroll
        for (int off = 32; off; off >>= 1) v += __shfl_xor(v, off);
        g[n] = v;
    }
    int qc = s >> 8;
    const double INF = __builtin_inf();
    #pragma unroll
    for (int n = 0; n < 8; ++n) {
        if (n == qc)                g[n] = INF;
        else if (s < (n + 1) * 256) g[n] = -INF;
    }
    unsigned int msk = 0;
    for (int p = 0; p < 4; ++p) {   // iterative argmax; strict > => lowest index on ties
        double best = -INF; int bi = -1;
        #pragma unroll
        for (int n = 0; n < 8; ++n)
            if (!((msk >> n) & 1) && g[n] > best) { best = g[n]; bi = n; }
        if (bi >= 0) msk |= 1u << bi;
    }
    if (lane == 0) {
        maskbuf[wid] = msk;
        if (qc >= 4) {   // only then can selection be ambiguous
            double worst_in = INF, best_out = -INF;
            #pragma unroll
            for (int n = 0; n < 8; ++n) {
                if ((msk >> n) & 1) worst_in = fmin(worst_in, g[n]);
                else if (g[n] > -1e300) best_out = fmax(best_out, g[n]);
            }
            if (worst_in - best_out < TAU) {
                int ix = atomicAdd(flagcnt, 1);
                flaglist[ix] = wid;
            }
        }
    }
}

// ---------- exact fp64 repair of flagged queries ----------
__global__ __launch_bounds__(256)
void repair_kernel(const float* __restrict__ hs, const float* __restrict__ wq,
                   const float* __restrict__ ct, const float* __restrict__ st,
                   const double* __restrict__ km, const int* __restrict__ flagcnt,
                   const int* __restrict__ flaglist, unsigned int* __restrict__ maskbuf) {
    __shared__ double red[256];
    __shared__ double qs[128];
    int nflag = *flagcnt;
    int t = threadIdx.x;
    int d = t & 127, half = t >> 7;
    for (int idx = blockIdx.x; idx < nflag; idx += gridDim.x) {
        int wid = flaglist[idx];
        int s = wid & 2047;
        int h = (wid >> 11) & 15;
        int b = wid >> 15;
        int kvh = h >> 2;
        const float* hrow = hs + (size_t)(b * 2048 + s) * 2048 + half * 1024;
        const float* wcol = wq + (size_t)half * 1024 * 2048 + h * 128 + d;
        double acc = 0.0;
        #pragma unroll 4
        for (int k = 0; k < 1024; ++k)
            acc = fma((double)hrow[k], (double)wcol[(size_t)k * 2048], acc);
        red[t] = acc;
        __syncthreads();
        if (t < 128) qs[t] = red[t] + red[t + 128];
        __syncthreads();
        if (t < 64) {
            double c  = (double)ct[s * 64 + t];
            double sn = (double)st[s * 64 + t];
            double x1 = qs[t], x2 = qs[t + 64];
            qs[t]      = x1 * c - x2 * sn;
            qs[t + 64] = x2 * c + x1 * sn;
        }
        __syncthreads();
        if (t < 64) {
            double g[8];
            #pragma unroll
            for (int n = 0; n < 8; ++n) {
                size_t kb = (size_t)((b * 8 + n) * 4 + kvh) * 128;
                double v = qs[t] * km[kb + t] + qs[t + 64] * km[kb + 64 + t];
                #pragma unroll
                for (int off = 32; off; off >>= 1) v += __shfl_xor(v, off);
                g[n] = v;
            }
            int qc = s >> 8;
            const double INF = __builtin_inf();
            #pragma unroll
            for (int n = 0; n < 8; ++n) {
                if (n == qc)                g[n] = INF;
                else if (s < (n + 1) * 256) g[n] = -INF;
            }
            unsigned int msk = 0;
            for (int p = 0; p < 4; ++p) {
                double best = -INF; int bi = -1;
                #pragma unroll
                for (int n = 0; n < 8; ++n)
                    if (!((msk >> n) & 1) && g[n] > best) { best = g[n]; bi = n; }
                if (bi >= 0) msk |= 1u << bi;
            }
            if (t == 0) maskbuf[wid] = msk;
        }
        __syncthreads();
    }
}

// ================= fp16 value path =================

__global__ void split_kernel(const float* __restrict__ src,
                             unsigned short* __restrict__ hi, int n4) {
    int i = blockIdx.x * 256 + threadIdx.x;
    if (i >= n4) return;
    float4 v = ((const float4*)src)[i];
    ushort4 h;
    h.x = f2h(v.x); h.y = f2h(v.y); h.z = f2h(v.z); h.w = f2h(v.w);
    ((ushort4*)hi)[i] = h;
}

__global__ void packw_kernel(const float* __restrict__ wq, const float* __restrict__ wk,
                             const float* __restrict__ wv, unsigned short* __restrict__ Wh) {
    int gid = blockIdx.x * 256 + threadIdx.x;   // 3072 * 512
    int n  = gid % 3072;
    int kg = gid / 3072;
    const float* src; int ldn, col;
    if (n < 2048)      { src = wq; ldn = 2048; col = n; }
    else if (n < 2560) { src = wk; ldn = 512;  col = n - 2048; }
    else               { src = wv; ldn = 512;  col = n - 2560; }
    int k0 = kg * 4;
    ushort4 h;
    h.x = f2h(src[(size_t)(k0 + 0) * ldn + col]);
    h.y = f2h(src[(size_t)(k0 + 1) * ldn + col]);
    h.z = f2h(src[(size_t)(k0 + 2) * ldn + col]);
    h.w = f2h(src[(size_t)(k0 + 3) * ldn + col]);
    *(ushort4*)&Wh[(size_t)n * 2048 + k0] = h;
}

__global__ void packwo_kernel(const float* __restrict__ wo, unsigned short* __restrict__ Wh) {
    int gid = blockIdx.x * 256 + threadIdx.x;   // 2048 * 512
    int n  = gid % 2048;
    int kg = gid / 2048;
    int k0 = kg * 4;
    ushort4 h;
    h.x = f2h(wo[(size_t)(k0 + 0) * 2048 + n]);
    h.y = f2h(wo[(size_t)(k0 + 1) * 2048 + n]);
    h.z = f2h(wo[(size_t)(k0 + 2) * 2048 + n]);
    h.w = f2h(wo[(size_t)(k0 + 3) * 2048 + n]);
    *(ushort4*)&Wh[(size_t)n * 2048 + k0] = h;
}

__global__ __launch_bounds__(256, 2)
void gemm_kernel(const unsigned short* __restrict__ A_g, const unsigned short* __restrict__ B_g,
                 float* __restrict__ Cg, int M, int N, int K) {
    const int BK = 32;
    __shared__ unsigned short Ah[128][BK + 8];
    __shared__ unsigned short Bh[128][BK + 8];
    int n0 = blockIdx.x * 128, m0 = blockIdx.y * 128;
    int t = threadIdx.x;
    int wave = t >> 6, lane = t & 63;
    int quad = lane >> 4, l15 = lane & 15;
    int wm = (wave >> 1) * 64, wn = (wave & 1) * 64;

    f32x4 acc[4][4];
    f32x4 zero = {0.f, 0.f, 0.f, 0.f};
    for (int i = 0; i < 4; ++i)
        for (int j = 0; j < 4; ++j) acc[i][j] = zero;

    int srow = t >> 3;
    int scol = (t & 7) * 4;

    for (int k0 = 0; k0 < K; k0 += BK) {
        __syncthreads();
        #pragma unroll
        for (int it = 0; it < 4; ++it) {
            int r = srow + it * 32;
            *(ushort4*)&Ah[r][scol] = *(const ushort4*)&A_g[(size_t)(m0 + r) * K + k0 + scol];
            *(ushort4*)&Bh[r][scol] = *(const ushort4*)&B_g[(size_t)(n0 + r) * K + k0 + scol];
        }
        __syncthreads();
        f16x8 ah[4], bh[4];
        #pragma unroll
        for (int i = 0; i < 4; ++i) {
            ah[i] = *(const f16x8*)&Ah[wm + i * 16 + l15][quad * 8];
            bh[i] = *(const f16x8*)&Bh[wn + i * 16 + l15][quad * 8];
        }
        #pragma unroll
        for (int i = 0; i < 4; ++i)
            #pragma unroll
            for (int j = 0; j < 4; ++j)
                acc[i][j] = __builtin_amdgcn_mfma_f32_16x16x32_f16(ah[i], bh[j], acc[i][j], 0, 0, 0);
    }
    #pragma unroll
    for (int i = 0; i < 4; ++i)
        #pragma unroll
        for (int j = 0; j < 4; ++j)
            #pragma unroll
            for (int r = 0; r < 4; ++r) {
                int row = m0 + wm + i * 16 + quad * 4 + r;
                int col = n0 + wn + j * 16 + l15;
                Cg[(size_t)row * N + col] = acc[i][j][r];
            }
}

__global__ void rope_kernel(float* __restrict__ C, const float* __restrict__ ct,
                            const float* __restrict__ st) {
    int gid = blockIdx.x * 256 + threadIdx.x;   // 4096*20*64
    int i   = gid & 63;
    int rem = gid >> 6;
    int head = rem % 20;
    int m    = rem / 20;
    int s = m & 2047;
    float cs = ct[s * 64 + i], sn = st[s * 64 + i];
    size_t base = (size_t)m * 3072 + head * 128;
    float x1 = C[base + i], x2 = C[base + i + 64];
    C[base + i]      = x1 * cs - x2 * sn;
    C[base + i + 64] = x2 * cs + x1 * sn;
}

// ---------- kv prep: K -> fp16 row-major, V -> fp16 transposed ----------
__global__ void kvprep_kernel(const float* __restrict__ C, unsigned short* __restrict__ Kh,
                              unsigned short* __restrict__ Vt) {
    __shared__ unsigned short vt[128][72];
    int blk = blockIdx.x;          // (b*4+kvh)*32 + kt
    int kt = blk & 31, kvh = (blk >> 5) & 3, b = blk >> 7;
    int t = threadIdx.x;
    int key0 = kt * 64;
    #pragma unroll
    for (int it = 0; it < 8; ++it) {
        int idx = t + it * 256;
        int r = idx >> 5, c = (idx & 31) * 4;
        size_t rowb = (size_t)(b * 2048 + key0 + r) * 3072;
        float4 kv = *(const float4*)&C[rowb + 2048 + kvh * 128 + c];
        ushort4 u; u.x = f2h(kv.x); u.y = f2h(kv.y); u.z = f2h(kv.z); u.w = f2h(kv.w);
        *(ushort4*)&Kh[((size_t)(b * 4 + kvh) * 2048 + key0 + r) * 128 + c] = u;
        float4 vv = *(const float4*)&C[rowb + 2560 + kvh * 128 + c];
        vt[c + 0][r] = f2h(vv.x); vt[c + 1][r] = f2h(vv.y);
        vt[c + 2][r] = f2h(vv.z); vt[c + 3][r] = f2h(vv.w);
    }
    __syncthreads();
    #pragma unroll
    for (int it = 0; it < 8; ++it) {
        int idx = t + it * 256;
        int d = idx >> 4, c4 = (idx & 15) * 4;
        *(ushort4*)&Vt[((size_t)(b * 4 + kvh) * 128 + d) * 2048 + key0 + c4] =
            *(ushort4*)&vt[d][c4];
    }
}

// ---------- MFMA flash attention ----------
__global__ __launch_bounds__(256, 2)
void attn_kernel(const float* __restrict__ C, const unsigned short* __restrict__ Kh,
                 const unsigned short* __restrict__ Vt,
                 const unsigned int* __restrict__ maskbuf,
                 unsigned short* __restrict__ Og) {
    __shared__ unsigned short q_s[64][136];
    __shared__ unsigned short k_s[64][136];
    __shared__ unsigned short v_t[128][72];
    __shared__ unsigned short p_s[64][72];
    __shared__ unsigned int umask;
    int bid = blockIdx.x;                     // (b*16+h)*32 + qt
    int qt = bid & 31, h = (bid >> 5) & 15, b = bid >> 9;
    int t = threadIdx.x;
    int wave = t >> 6, lane = t & 63;
    int quad = lane >> 4, l15 = lane & 15;
    int w16 = wave * 16;
    int q0 = qt * 64, qc = q0 >> 8, kvh = h >> 2;
    const float NEGINF = -__builtin_inff();

    #pragma unroll
    for (int it = 0; it < 8; ++it) {
        int idx = t + it * 256;
        int r = idx >> 5, c = (idx & 31) * 4;
        float4 v4 = *(const float4*)&C[(size_t)(b * 2048 + q0 + r) * 3072 + h * 128 + c];
        ushort4 u; u.x = f2h(v4.x); u.y = f2h(v4.y); u.z = f2h(v4.z); u.w = f2h(v4.w);
        *(ushort4*)&q_s[r][c] = u;
    }
    if (t == 0) umask = 0;
    int mbase = ((b * 16 + h) << 11) + q0;
    unsigned int am[4];
    #pragma unroll
    for (int r = 0; r < 4; ++r)
        am[r] = maskbuf[mbase + w16 + quad * 4 + r];
    __syncthreads();
    if (t < 64) atomicOr(&umask, maskbuf[mbase + t]);
    f16x8 aq[4];
    #pragma unroll
    for (int ks = 0; ks < 4; ++ks)
        aq[ks] = *(const f16x8*)&q_s[w16 + l15][ks * 32 + quad * 8];
    __syncthreads();
    unsigned int um = umask;

    float m_i[4], l_i[4];
    f32x4 o_acc[8];
    #pragma unroll
    for (int r = 0; r < 4; ++r) { m_i[r] = NEGINF; l_i[r] = 0.f; }
    #pragma unroll
    for (int n = 0; n < 8; ++n) o_acc[n] = (f32x4){0.f, 0.f, 0.f, 0.f};
    const float scale = 0.08838834764831845f;
    size_t khbase = (size_t)(b * 4 + kvh) * 2048 * 128;
    size_t vtbase = (size_t)(b * 4 + kvh) * 128 * 2048;

    for (int c = 0; c <= qc; ++c) {
        if (!((um >> c) & 1)) continue;
        int submax = (c == qc) ? ((q0 & 255) >> 6) : 3;
        for (int sub = 0; sub <= submax; ++sub) {
            int kbase = c * 256 + sub * 64;
            __syncthreads();
            #pragma unroll
            for (int it = 0; it < 8; ++it) {
                int idx = t + it * 256;
                int r = idx >> 5, cc = (idx & 31) * 4;
                *(ushort4*)&k_s[r][cc] =
                    *(const ushort4*)&Kh[khbase + (size_t)(kbase + r) * 128 + cc];
                int vr = idx >> 4, vc = (idx & 15) * 4;
                *(ushort4*)&v_t[vr][vc] =
                    *(const ushort4*)&Vt[vtbase + (size_t)vr * 2048 + kbase + vc];
            }
            __syncthreads();
            f32x4 s[4];
            #pragma unroll
            for (int j = 0; j < 4; ++j) {
                f32x4 sj = {0.f, 0.f, 0.f, 0.f};
                #pragma unroll
                for (int ks = 0; ks < 4; ++ks) {
                    f16x8 bf = *(const f16x8*)&k_s[j * 16 + l15][ks * 32 + quad * 8];
                    sj = __builtin_amdgcn_mfma_f32_16x16x32_f16(aq[ks], bf, sj, 0, 0, 0);
                }
                s[j] = sj;
            }
            #pragma unroll
            for (int r = 0; r < 4; ++r) {
                int qpos = q0 + w16 + quad * 4 + r;
                bool allow = (am[r] >> c) & 1;
                float sv[4], rmax = NEGINF;
                #pragma unroll
                for (int j = 0; j < 4; ++j) {
                    int kpos = kbase + j * 16 + l15;
                    float x = s[j][r] * scale;
                    if (!allow || kpos > qpos) x = NEGINF;
                    sv[j] = x;
                    rmax = fmaxf(rmax, x);
                }
                rmax = fmaxf(rmax, __shfl_xor(rmax, 1));
                rmax = fmaxf(rmax, __shfl_xor(rmax, 2));
                rmax = fmaxf(rmax, __shfl_xor(rmax, 4));
                rmax = fmaxf(rmax, __shfl_xor(rmax, 8));
                float mnew = fmaxf(m_i[r], rmax);
                float alpha = (m_i[r] == NEGINF) ? 0.f : __expf(m_i[r] - mnew);
                float ps[4], lsum = 0.f;
                #pragma unroll
                for (int j = 0; j < 4; ++j) {
                    float p = (sv[j] == NEGINF) ? 0.f : __expf(sv[j] - mnew);
                    ps[j] = p; lsum += p;
                }
                lsum += __shfl_xor(lsum, 1);
                lsum += __shfl_xor(lsum, 2);
                lsum += __shfl_xor(lsum, 4);
                lsum += __shfl_xor(lsum, 8);
                l_i[r] = l_i[r] * alpha + lsum;
                m_i[r] = mnew;
                #pragma unroll
                for (int n = 0; n < 8; ++n) o_acc[n][r] *= alpha;
                #pragma unroll
                for (int j = 0; j < 4; ++j)
                    p_s[w16 + quad * 4 + r][j * 16 + l15] = f2h(ps[j]);
            }
            f16x8 pa0 = *(const f16x8*)&p_s[w16 + l15][quad * 8];
            f16x8 pa1 = *(const f16x8*)&p_s[w16 + l15][32 + quad * 8];
            #pragma unroll
            for (int n = 0; n < 8; ++n) {
                f16x8 b0 = *(const f16x8*)&v_t[n * 16 + l15][quad * 8];
                f16x8 b1 = *(const f16x8*)&v_t[n * 16 + l15][32 + quad * 8];
                o_acc[n] = __builtin_amdgcn_mfma_f32_16x16x32_f16(pa0, b0, o_acc[n], 0, 0, 0);
                o_acc[n] = __builtin_amdgcn_mfma_f32_16x16x32_f16(pa1, b1, o_acc[n], 0, 0, 0);
            }
        }
    }
    __syncthreads();
    #pragma unroll
    for (int r = 0; r < 4; ++r) {
        float inv = (l_i[r] > 0.f) ? 1.f / l_i[r] : 0.f;
        #pragma unroll
        for (int n = 0; n < 8; ++n)
            q_s[w16 + quad * 4 + r][n * 16 + l15] = f2h(o_acc[n][r] * inv);
    }
    __syncthreads();
    #pragma unroll
    for (int it = 0; it < 8; ++it) {
        int idx = t + it * 256;
        int r = idx >> 5, cpos = (idx & 31) * 4;
        *(ushort4*)&Og[(size_t)(b * 2048 + q0 + r) * 2048 + h * 128 + cpos] =
            *(ushort4*)&q_s[r][cpos];
    }
}

// ---------- launch ----------
extern "C" void kernel_launch(void* const* d_in, const int* in_sizes, int n_in,
                              void* d_out, int out_size, void* d_ws, size_t ws_size,
                              hipStream_t stream) {
    const float* hs = (const float*)d_in[0];
    const float* wq = (const float*)d_in[1];
    const float* wk = (const float*)d_in[2];
    const float* wv = (const float*)d_in[3];
    const float* wo = (const float*)d_in[4];
    float* out = (float*)d_out;
    char* ws = (char*)d_ws;

    // phase-1 (gate) buffers, overlapped with the Cqkv region (consumed before
    // the fp16 QKV GEMM writes Cqkv):
    double*         Act  = (double*)       (ws + 37748736);    // 16.78 MB
    double*         Ast  = (double*)       (ws + 54525952);    // 16.78 MB
    // phase-2 buffers:
    unsigned short* hsh  = (unsigned short*)(ws + 0);          // 16.78 MB
    unsigned short* Wth  = (unsigned short*)(ws + 16777216);   // 12.58 MB
    unsigned short* woth = (unsigned short*)(ws + 29360128);   //  8.39 MB
    float*          Cqkv = (float*)        (ws + 37748736);    // 50.33 MB
    unsigned short* Og   = (unsigned short*)(ws + 88080384);   // 16.78 MB
    // persistent:
    double*         km64 = (double*)       (ws + 104857600);   // 64 KB
    unsigned int*   mskb = (unsigned int*) (ws + 104923136);   // 512 KB
    float*          ct   = (float*)        (ws + 105447424);   // 512 KB
    float*          st   = (float*)        (ws + 105971712);   // 512 KB
    unsigned short* Kh   = (unsigned short*)(ws + 106496000);  //  8.39 MB
    unsigned short* Vt   = (unsigned short*)(ws + 114884608);  //  8.39 MB
    int*            fcnt = (int*)          (ws + 123273216);   // 64 B
    int*            flst = (int*)          (ws + 123273280);   // 256 KB (total ~123.5 MB)

    // phase 1: exact km64 via rope-factorized trig-weighted sums
    sctab_kernel  <<<512, 256, 0, stream>>>(ct, st);
    ksum_kernel   <<<dim3(32, 16), 256, 0, stream>>>(hs, ct, st, Act, Ast);
    kmzero_kernel <<<32, 256, 0, stream>>>(km64);
    kmeanw_kernel <<<256, 256, 0, stream>>>(Act, Ast, wk, km64);
    // phase 2: fp16 value path (also feeds provisional gates)
    split_kernel  <<<8192, 256, 0, stream>>>(hs, hsh, 2097152);
    packw_kernel  <<<6144, 256, 0, stream>>>(wq, wk, wv, Wth);
    packwo_kernel <<<4096, 256, 0, stream>>>(wo, woth);
    gemm_kernel   <<<dim3(24, 32), 256, 0, stream>>>(hsh, Wth, Cqkv, 4096, 3072, 2048);
    rope_kernel   <<<20480, 256, 0, stream>>>(Cqkv, ct, st);
    // gates: provisional + margin-filtered exact repair
    zeroflag_kernel<<<1, 64, 0, stream>>>(fcnt);
    gatebase_kernel<<<16384, 256, 0, stream>>>(Cqkv, km64, mskb, fcnt, flst);
    repair_kernel <<<2048, 256, 0, stream>>>(hs, wq, ct, st, km64, fcnt, flst, mskb);
    // attention + out-proj
    kvprep_kernel <<<256, 256, 0, stream>>>(Cqkv, Kh, Vt);
    attn_kernel   <<<1024, 256, 0, stream>>>(Cqkv, Kh, Vt, mskb, Og);
    gemm_kernel   <<<dim3(16, 32), 256, 0, stream>>>(Og, woth, out, 4096, 2048, 2048);
}